// Round 1
// baseline (2883.120 us; speedup 1.0000x reference)
//
#include <hip/hip_runtime.h>
#include <math.h>

#define Bv 256
#define Dv 38
#define Sv 64
#define SWv 10
#define EPSv 1e-5f

__device__ __forceinline__ float leaky(float v){ return v > 0.f ? v : 0.01f*v; }
__device__ __forceinline__ float sigm(float v){ return 1.f/(1.f+expf(-v)); }

__device__ __forceinline__ float wred64(float v){
  #pragma unroll
  for (int off=32; off; off>>=1) v += __shfl_xor(v, off, 64);
  return v;
}
__device__ __forceinline__ float wred32(float v){
  #pragma unroll
  for (int off=16; off; off>>=1) v += __shfl_xor(v, off, 32);
  return v;
}
__device__ __forceinline__ float wmax64(float v){
  #pragma unroll
  for (int off=32; off; off>>=1) v = fmaxf(v, __shfl_xor(v, off, 64));
  return v;
}

// ---------------- K1: FE1 + conv/pool + embed + wq + v/wv ----------------
__global__ __launch_bounds__(256) void k1_fe(
    const float* __restrict__ x, const float* __restrict__ W1, const float* __restrict__ b1,
    const float* __restrict__ W2, const float* __restrict__ b2,
    const float* __restrict__ Wl, const float* __restrict__ bl,
    const float* __restrict__ Wq, const float* __restrict__ bq,
    const float* __restrict__ Wv1, const float* __restrict__ bv1,
    const float* __restrict__ lnvg, const float* __restrict__ lnvb,
    const float* __restrict__ Wv2, const float* __restrict__ bv2,
    float* __restrict__ e_ws, float* __restrict__ wq_ws, float* __restrict__ wv_ws)
{
  const int blk = blockIdx.x;
  const int b = blk / Dv, d = blk % Dv;
  const int tid = threadIdx.x;
  const int g = tid >> 6, lane = tid & 63;

  __shared__ float W1s[64][11];     // pad 10->11 (coprime 32): conflict-free
  __shared__ float Wls[64][125];    // pad 124->125
  __shared__ float Wv1s[32][65];    // pad 64->65
  __shared__ float W2s[4][3];
  __shared__ float b1s[64], bls[64], Wqs[64];
  __shared__ float b2s[4];
  __shared__ float bv1s[32], lnvgs[32], lnvbs[32], Wv2s[32];
  __shared__ float f1p[4][66];      // padded FE1 output per s-group
  __shared__ float ms[4][124];
  __shared__ float es[4][64];

  for (int i=tid; i<640; i+=256)  W1s[i/10][i%10]   = W1[d*640+i];
  for (int i=tid; i<7936; i+=256) Wls[i/124][i%124] = Wl[d*7936+i];
  for (int i=tid; i<2048; i+=256) Wv1s[i>>6][i&63]  = Wv1[d*2048+i];
  if (tid < 64) { b1s[tid]=b1[d*64+tid]; bls[tid]=bl[d*64+tid]; Wqs[tid]=Wq[tid]; }
  if (tid < 32) { bv1s[tid]=bv1[d*32+tid]; lnvgs[tid]=lnvg[d*32+tid];
                  lnvbs[tid]=lnvb[d*32+tid]; Wv2s[tid]=Wv2[d*32+tid]; }
  if (tid < 12) W2s[tid/3][tid%3] = W2[d*12+tid];
  if (tid < 4)  b2s[tid] = b2[d*4+tid];
  if (tid < 4)  { f1p[tid][0]=0.f; f1p[tid][65]=0.f; }
  __syncthreads();

  const float bq0 = bq[0], bv2d = bv2[d];
  const int bd = b*Dv + d;
  const float* xrow = x + (size_t)bd*640;

  for (int s = g; s < Sv; s += 4) {
    // FE1: 10 -> 64 per-dim matvec
    float a = b1s[lane];
    const float* xs = xrow + s*SWv;
    #pragma unroll
    for (int w=0; w<SWv; ++w) a += xs[w]*W1s[lane][w];
    f1p[g][lane+1] = leaky(a);
    __syncthreads();

    // FE2 conv(k=3,p=1) + maxpool(3,stride 2) fused: lane i -> m[ch][i], i<31
    if (lane < 31) {
      #pragma unroll
      for (int ch=0; ch<4; ++ch) {
        float mx = -1e30f;
        #pragma unroll
        for (int t3=0; t3<3; ++t3) {
          int t = 2*lane + t3;
          float cc = b2s[ch];
          #pragma unroll
          for (int r=0; r<3; ++r) cc += f1p[g][t+r]*W2s[ch][r];
          mx = fmaxf(mx, leaky(cc));
        }
        ms[g][ch*31+lane] = mx;
      }
    }
    __syncthreads();

    // embed: 124 -> 64
    float ea = bls[lane];
    #pragma unroll 4
    for (int f=0; f<124; ++f) ea += ms[g][f]*Wls[lane][f];
    float ev = leaky(ea);
    es[g][lane] = ev;
    e_ws[((size_t)bd*Sv + s)*64 + lane] = ev;

    // wq
    float p = wred64(ev * Wqs[lane]);
    if (lane==0) wq_ws[bd*Sv + s] = sigm(p + bq0);
    __syncthreads();

    // v: 64 -> 32, LN over 32, wv
    float zv = 0.f;
    if (lane < 32) {
      zv = bv1s[lane];
      for (int o=0;o<64;++o) zv += es[g][o]*Wv1s[lane][o];
    }
    float s1 = wred32(zv), s2 = wred32(zv*zv);
    float mu = s1*(1.f/32.f);
    float var = s2*(1.f/32.f) - mu*mu;
    float vh = leaky(lnvgs[lane&31]*(zv-mu)*rsqrtf(var+EPSv) + lnvbs[lane&31]);
    float q = wred32(vh * Wv2s[lane&31]);
    if (lane==0) wv_ws[bd*Sv + s] = fmaxf(q + bv2d, 0.f);
    __syncthreads();
  }
}

// ---------------- K2: Wb1+LN+Wb2, cumsum, wk·wq -> score1 ----------------
__global__ __launch_bounds__(256) void k2_rec(
    const float* __restrict__ e_ws,
    const float* __restrict__ Wb1, const float* __restrict__ bb1,
    const float* __restrict__ lng, const float* __restrict__ lnb,
    const float* __restrict__ Wb2, const float* __restrict__ bb2,
    const float* __restrict__ Wk, const float* __restrict__ bk,
    const float* __restrict__ wq_ws, float* __restrict__ score1)
{
  const int blk = blockIdx.x;
  const int b = blk / Dv, d = blk % Dv;
  const int tid = threadIdx.x;
  const int g = tid >> 6, lane = tid & 63;

  __shared__ float es2[64][64];   // [s][o]
  __shared__ float gb[64][64];    // [s][q] -> cumsum in place
  __shared__ float hs[4][64];
  __shared__ float bb1s[64], bb2s[64], lngs[64], lnbs[64];
  __shared__ float bks[38];

  const size_t ebase = (size_t)(b*Dv+d)*Sv*64;
  for (int i=tid;i<4096;i+=256) (&es2[0][0])[i] = e_ws[ebase+i];
  if (tid<64){ bb1s[tid]=bb1[tid]; bb2s[tid]=bb2[tid]; lngs[tid]=lng[tid]; lnbs[tid]=lnb[tid]; }
  if (tid<38) bks[tid]=bk[tid];
  __syncthreads();

  for (int s=g; s<Sv; s+=4) {
    float z = bb1s[lane];
    const float* wrow = Wb1 + lane*64;
    for (int o=0;o<64;++o) z += es2[s][o]*wrow[o];
    float s1 = wred64(z), s2 = wred64(z*z);
    float mu = s1*(1.f/64.f), var = s2*(1.f/64.f)-mu*mu;
    float hh = leaky(lngs[lane]*(z-mu)*rsqrtf(var+EPSv)+lnbs[lane]);
    hs[g][lane] = hh;
    __syncthreads();
    float gg = bb2s[lane];
    const float* w2row = Wb2 + lane*64;
    for (int p=0;p<64;++p) gg += hs[g][p]*w2row[p];
    gb[s][lane] = leaky(gg);
    __syncthreads();
  }
  // cumsum over time
  if (tid < 64) {
    float acc = 0.f;
    for (int s=0;s<Sv;++s){ acc += gb[s][tid]; gb[s][tid]=acc; }
  }
  __syncthreads();
  // score1[b,s,d] = sum_k wq[b,k,s] * sigmoid(acml[b,d,s]·Wk[k]+bk[k])
  for (int s=g; s<Sv; s+=4) {
    float pr = 0.f;
    if (lane < Dv) {
      float u = bks[lane];
      const float* wkr = Wk + lane*64;
      for (int o=0;o<64;++o) u += gb[s][o]*wkr[o];
      pr = sigm(u) * wq_ws[(b*Dv+lane)*Sv + s];
    }
    pr = wred64(pr);
    if (lane==0) score1[(b*Sv+s)*Dv + d] = pr;
  }
}

// ---------------- K3: att1 softmax + contributes1/output1 + wq_a ----------------
__global__ __launch_bounds__(256) void k3_att1(
    const float* __restrict__ score1, const float* __restrict__ wv_ws,
    const float* __restrict__ e_ws, const float* __restrict__ Wq2, const float* __restrict__ bq2,
    float* __restrict__ out_c1, float* __restrict__ output1, float* __restrict__ wq_a)
{
  const int blk = blockIdx.x;
  const int b = blk / Sv, s = blk % Sv;
  const int tid = threadIdx.x;
  const int wid = tid>>6, lane = tid&63;
  __shared__ float red[4];

  if (wid==0) {
    const float invsq = 0.16222142113076254f; // 1/sqrt(38)
    float sc = (lane<Dv) ? score1[(b*Sv+s)*Dv+lane]*invsq : -1e30f;
    float mx = wmax64(sc);
    float ex = (lane<Dv) ? expf(sc-mx) : 0.f;
    float den = wred64(ex);
    float att = ex/den;
    float c1 = 0.f;
    if (lane<Dv) {
      c1 = wv_ws[(b*Dv+lane)*Sv+s]*att;
      out_c1[(b*Sv+s)*Dv+lane] = c1;
    }
    float tot = wred64(c1);
    if (lane==0) output1[b*Sv+s] = tot;
  }
  // wq_a[b,s] = sigmoid(ef[b,s]·Wq2 + bq2)
  float p = 0.f;
  for (int idx=tid; idx<Dv*64; idx+=256) {
    int d = idx>>6, o = idx&63;
    p += e_ws[((size_t)(b*Dv+d)*Sv+s)*64+o]*Wq2[idx];
  }
  p = wred64(p);
  if (lane==0) red[wid]=p;
  __syncthreads();
  if (tid==0) wq_a[b*Sv+s] = sigm(red[0]+red[1]+red[2]+red[3]+bq2[0]);
}

// ---------------- K4: score2[b,t] = sum_s wq_a[b,s]*sigmoid(ef[b,t]·Wk2[s]+bk2[s]) ----------------
__global__ __launch_bounds__(256) void k4_score2(
    const float* __restrict__ e_ws, const float* __restrict__ Wk2, const float* __restrict__ bk2,
    const float* __restrict__ wq_a, float* __restrict__ score2)
{
  const int blk = blockIdx.x;
  const int b = blk / Sv, t = blk % Sv;
  const int tid = threadIdx.x;
  const int w = tid>>6, lane = tid&63;
  __shared__ float efs[Dv*64];
  __shared__ float part[4];
  for (int idx=tid; idx<Dv*64; idx+=256)
    efs[idx] = e_ws[((size_t)(b*Dv+(idx>>6))*Sv+t)*64+(idx&63)];
  __syncthreads();
  float acc = 0.f;
  for (int s=w; s<Sv; s+=4) {
    const float* wrow = Wk2 + s*(Dv*64);
    float p = 0.f;
    for (int j=lane;j<Dv*64;j+=64) p += efs[j]*wrow[j];
    p = wred64(p);
    acc += sigm(p + bk2[s]) * wq_a[b*Sv+s];
  }
  if (lane==0) part[w]=acc;
  __syncthreads();
  if (tid==0) score2[b*Sv+t]=part[0]+part[1]+part[2]+part[3];
}

// ---------------- K5: att2 softmax + contributes2/output2 ----------------
__global__ __launch_bounds__(64) void k5_final(
    const float* __restrict__ score2, const float* __restrict__ output1,
    float* __restrict__ out)
{
  const int b = blockIdx.x;
  const int lane = threadIdx.x;
  const float inv = 0.039528470752104741f; // 1/sqrt(640)
  float v = score2[b*Sv+lane]*inv;
  float mx = wmax64(v);
  float ex = expf(v-mx);
  float den = wred64(ex);
  float att = ex/den;
  float c2 = output1[b*Sv+lane]*att;
  out[256 + b*Sv + lane] = c2;     // contributes2
  float tot = wred64(c2);
  if (lane==0) out[b] = tot;       // output2
}

extern "C" void kernel_launch(void* const* d_in, const int* in_sizes, int n_in,
                              void* d_out, int out_size, void* d_ws, size_t ws_size,
                              hipStream_t stream)
{
  const float* x    = (const float*)d_in[0];
  const float* W1   = (const float*)d_in[1];
  const float* b1   = (const float*)d_in[2];
  const float* W2   = (const float*)d_in[3];
  const float* b2   = (const float*)d_in[4];
  const float* Wl   = (const float*)d_in[5];
  const float* bl   = (const float*)d_in[6];
  const float* Wb1  = (const float*)d_in[7];
  const float* bb1  = (const float*)d_in[8];
  const float* lng  = (const float*)d_in[9];
  const float* lnb  = (const float*)d_in[10];
  const float* Wb2  = (const float*)d_in[11];
  const float* bb2  = (const float*)d_in[12];
  const float* Wq   = (const float*)d_in[13];
  const float* bq   = (const float*)d_in[14];
  const float* Wk   = (const float*)d_in[15];
  const float* bk   = (const float*)d_in[16];
  const float* Wv1  = (const float*)d_in[17];
  const float* bv1  = (const float*)d_in[18];
  const float* lnvg = (const float*)d_in[19];
  const float* lnvb = (const float*)d_in[20];
  const float* Wv2  = (const float*)d_in[21];
  const float* bv2  = (const float*)d_in[22];
  const float* Wq2  = (const float*)d_in[23];
  const float* bq2  = (const float*)d_in[24];
  const float* Wk2  = (const float*)d_in[25];
  const float* bk2  = (const float*)d_in[26];

  float* ws = (float*)d_ws;
  float* e_ws  = ws;                                   // B*D*S*64 = 39,845,888 f
  float* wq_ws = e_ws + (size_t)Bv*Dv*Sv*64;           // B*D*S
  float* wv_ws = wq_ws + (size_t)Bv*Dv*Sv;             // B*D*S
  float* sc1   = wv_ws + (size_t)Bv*Dv*Sv;             // B*S*D
  float* out1  = sc1 + (size_t)Bv*Sv*Dv;               // B*S
  float* wqa   = out1 + (size_t)Bv*Sv;                 // B*S
  float* sc2   = wqa + (size_t)Bv*Sv;                  // B*S

  float* out = (float*)d_out;
  float* out_c1 = out + 256 + Bv*Sv;                   // contributes1 offset

  hipLaunchKernelGGL(k1_fe, dim3(Bv*Dv), dim3(256), 0, stream,
    x, W1, b1, W2, b2, Wl, bl, Wq, bq, Wv1, bv1, lnvg, lnvb, Wv2, bv2,
    e_ws, wq_ws, wv_ws);
  hipLaunchKernelGGL(k2_rec, dim3(Bv*Dv), dim3(256), 0, stream,
    e_ws, Wb1, bb1, lng, lnb, Wb2, bb2, Wk, bk, wq_ws, sc1);
  hipLaunchKernelGGL(k3_att1, dim3(Bv*Sv), dim3(256), 0, stream,
    sc1, wv_ws, e_ws, Wq2, bq2, out_c1, out1, wqa);
  hipLaunchKernelGGL(k4_score2, dim3(Bv*Sv), dim3(256), 0, stream,
    e_ws, Wk2, bk2, wqa, sc2);
  hipLaunchKernelGGL(k5_final, dim3(Bv), dim3(64), 0, stream, sc2, out1, out);
}

// Round 2
// 1558.368 us; speedup vs baseline: 1.8501x; 1.8501x over previous
//
#include <hip/hip_runtime.h>
#include <math.h>

#define Bv 256
#define Dv 38
#define Sv 64
#define SWv 10
#define EPSv 1e-5f

typedef float f4 __attribute__((ext_vector_type(4)));

__device__ __forceinline__ float leaky(float v){ return v > 0.f ? v : 0.01f*v; }
__device__ __forceinline__ float sigm(float v){ return 1.f/(1.f+expf(-v)); }

__device__ __forceinline__ float wred64(float v){
  #pragma unroll
  for (int off=32; off; off>>=1) v += __shfl_xor(v, off, 64);
  return v;
}
__device__ __forceinline__ float wred32(float v){
  #pragma unroll
  for (int off=16; off; off>>=1) v += __shfl_xor(v, off, 32);
  return v;
}
__device__ __forceinline__ float wmax64(float v){
  #pragma unroll
  for (int off=32; off; off>>=1) v = fmaxf(v, __shfl_xor(v, off, 64));
  return v;
}

// ---------------- K1: FE1 + conv/pool + embed + wq + v/wv ----------------
__global__ __launch_bounds__(256) void k1_fe(
    const float* __restrict__ x, const float* __restrict__ W1, const float* __restrict__ b1,
    const float* __restrict__ W2, const float* __restrict__ b2,
    const float* __restrict__ Wl, const float* __restrict__ bl,
    const float* __restrict__ Wq, const float* __restrict__ bq,
    const float* __restrict__ Wv1, const float* __restrict__ bv1,
    const float* __restrict__ lnvg, const float* __restrict__ lnvb,
    const float* __restrict__ Wv2, const float* __restrict__ bv2,
    float* __restrict__ e_ws, float* __restrict__ wq2_ws, float* __restrict__ wv_ws)
{
  const int blk = blockIdx.x;
  const int b = blk / Dv, d = blk % Dv;
  const int tid = threadIdx.x;
  const int g = tid >> 6, lane = tid & 63;

  __shared__ float W1s[64][11];     // pad 10->11: conflict-free
  __shared__ float Wls[64][125];    // pad 124->125
  __shared__ float Wv1s[32][65];    // pad 64->65
  __shared__ float W2s[4][3];
  __shared__ float b1s[64], bls[64], Wqs[64];
  __shared__ float b2s[4];
  __shared__ float bv1s[32], lnvgs[32], lnvbs[32], Wv2s[32];
  __shared__ float f1p[4][66];      // padded FE1 output per s-group
  __shared__ float ms[4][124];
  __shared__ float es[4][64];

  for (int i=tid; i<640; i+=256)  W1s[i/10][i%10]   = W1[d*640+i];
  for (int i=tid; i<7936; i+=256) Wls[i/124][i%124] = Wl[d*7936+i];
  for (int i=tid; i<2048; i+=256) Wv1s[i>>6][i&63]  = Wv1[d*2048+i];
  if (tid < 64) { b1s[tid]=b1[d*64+tid]; bls[tid]=bl[d*64+tid]; Wqs[tid]=Wq[tid]; }
  if (tid < 32) { bv1s[tid]=bv1[d*32+tid]; lnvgs[tid]=lnvg[d*32+tid];
                  lnvbs[tid]=lnvb[d*32+tid]; Wv2s[tid]=Wv2[d*32+tid]; }
  if (tid < 12) W2s[tid/3][tid%3] = W2[d*12+tid];
  if (tid < 4)  b2s[tid] = b2[d*4+tid];
  if (tid < 4)  { f1p[tid][0]=0.f; f1p[tid][65]=0.f; }
  __syncthreads();

  const float bq0 = bq[0], bv2d = bv2[d];
  const int bd = b*Dv + d;
  const float* xrow = x + (size_t)bd*640;

  for (int s = g; s < Sv; s += 4) {
    // FE1: 10 -> 64 per-dim matvec
    float a = b1s[lane];
    const float* xs = xrow + s*SWv;
    #pragma unroll
    for (int w=0; w<SWv; ++w) a += xs[w]*W1s[lane][w];
    f1p[g][lane+1] = leaky(a);
    __syncthreads();

    // FE2 conv(k=3,p=1) + maxpool(3,stride 2) fused: lane i -> m[ch][i], i<31
    if (lane < 31) {
      #pragma unroll
      for (int ch=0; ch<4; ++ch) {
        float mx = -1e30f;
        #pragma unroll
        for (int t3=0; t3<3; ++t3) {
          int t = 2*lane + t3;
          float cc = b2s[ch];
          #pragma unroll
          for (int r=0; r<3; ++r) cc += f1p[g][t+r]*W2s[ch][r];
          mx = fmaxf(mx, leaky(cc));
        }
        ms[g][ch*31+lane] = mx;
      }
    }
    __syncthreads();

    // embed: 124 -> 64
    float ea = bls[lane];
    #pragma unroll 4
    for (int f=0; f<124; ++f) ea += ms[g][f]*Wls[lane][f];
    float ev = leaky(ea);
    es[g][lane] = ev;
    e_ws[((size_t)bd*Sv + s)*64 + lane] = ev;

    // wq -> layout [b][s][k]
    float p = wred64(ev * Wqs[lane]);
    if (lane==0) wq2_ws[(b*Sv + s)*Dv + d] = sigm(p + bq0);
    __syncthreads();

    // v: 64 -> 32, LN over 32, wv
    float zv = 0.f;
    if (lane < 32) {
      zv = bv1s[lane];
      for (int o=0;o<64;++o) zv += es[g][o]*Wv1s[lane][o];
    }
    float s1 = wred32(zv), s2 = wred32(zv*zv);
    float mu = s1*(1.f/32.f);
    float var = s2*(1.f/32.f) - mu*mu;
    float vh = leaky(lnvgs[lane&31]*(zv-mu)*rsqrtf(var+EPSv) + lnvbs[lane&31]);
    float q = wred32(vh * Wv2s[lane&31]);
    if (lane==0) wv_ws[bd*Sv + s] = fmaxf(q + bv2d, 0.f);
    __syncthreads();
  }
}

// ---------------- K2: fused Wb1+LN+Wb2+cumsum+Wk/wq -> score1 ----------------
// grid 4864 blocks (2 (b,d)-groups = 128 rows each), 128 threads.
// Register tiles 8x8: rows {4tx..+3, 64+4tx..+3}, cols {4ty..+3, 32+4ty..+3}.
__global__ __launch_bounds__(128) void k2_fused(
    const float* __restrict__ e_ws,
    const float* __restrict__ Wb1, const float* __restrict__ bb1,
    const float* __restrict__ lng, const float* __restrict__ lnb,
    const float* __restrict__ Wb2, const float* __restrict__ bb2,
    const float* __restrict__ Wk, const float* __restrict__ bk,
    const float* __restrict__ wq2_ws, float* __restrict__ score1)
{
  __shared__ float smem[16384];           // 64 KiB, phase-aliased
  float* bufA = smem;                     // 8192 f  [64][128]: EsT -> HnT -> AcmlT
  float* bufB = smem + 8192;              // 4096 f  [64][64]:  W1T -> pts/ptq/stats -> WkT[64][40]
  float* bufC = smem + 12288;             // 4096 f  [64][64]:  W2T -> pt2[128][9]

  const int tid = threadIdx.x;
  const int tx = tid & 15;
  const int ty = tid >> 4;                // 0..7
  const int bd0 = blockIdx.x * 2;
  const int bd1 = bd0 + 1;

#define RI(i) ((i) < 4 ? 4*tx + (i) : 64 + 4*tx + ((i)-4))
#define PJ(j) ((j) < 4 ? 4*ty + (j) : 32 + 4*ty + ((j)-4))

  // ---- stage EsT (bufA), W1T (bufB), W2T (bufC), transposed ----
  {
    const int r0 = tid & 15, c0 = tid >> 4;      // c0 0..7
    const f4* Esrc  = (const f4*)(e_ws + (size_t)bd0 * 4096);
    #pragma unroll
    for (int p = 0; p < 2; ++p) {
      int oc = c0 + 8*p;
      #pragma unroll
      for (int q = 0; q < 8; ++q) {
        int r = r0 + 16*q;
        f4 v = Esrc[r*16 + oc];
        #pragma unroll
        for (int k = 0; k < 4; ++k) bufA[(4*oc+k)*128 + r] = v[k];
      }
    }
    const f4* W1src = (const f4*)Wb1;
    const f4* W2src = (const f4*)Wb2;
    #pragma unroll
    for (int p = 0; p < 2; ++p) {
      int oc = c0 + 8*p;
      #pragma unroll
      for (int q = 0; q < 4; ++q) {
        int rr = r0 + 16*q;
        f4 v1 = W1src[rr*16 + oc];
        f4 v2 = W2src[rr*16 + oc];
        #pragma unroll
        for (int k = 0; k < 4; ++k) {
          bufB[(4*oc+k)*64 + rr] = v1[k];
          bufC[(4*oc+k)*64 + rr] = v2[k];
        }
      }
    }
  }
  __syncthreads();

  // per-thread column constants
  float bb1v[8], lngv[8], lnbv[8], bb2v[8];
  #pragma unroll
  for (int j=0;j<8;++j) {
    int p = PJ(j);
    bb1v[j]=bb1[p]; lngv[j]=lng[p]; lnbv[j]=lnb[p]; bb2v[j]=bb2[p];
  }

  // ---- GEMM1: h[r][p] = sum_o E[r][o]*Wb1[p][o] ----
  float h[8][8];
  #pragma unroll
  for (int i=0;i<8;++i)
    #pragma unroll
    for (int j=0;j<8;++j) h[i][j]=0.f;
  for (int o = 0; o < 64; ++o) {
    f4 al = *(const f4*)(bufA + o*128 + 4*tx);
    f4 ah = *(const f4*)(bufA + o*128 + 64 + 4*tx);
    f4 bl = *(const f4*)(bufB + o*64 + 4*ty);
    f4 bh = *(const f4*)(bufB + o*64 + 32 + 4*ty);
    float av[8] = {al[0],al[1],al[2],al[3],ah[0],ah[1],ah[2],ah[3]};
    float bv[8] = {bl[0],bl[1],bl[2],bl[3],bh[0],bh[1],bh[2],bh[3]};
    #pragma unroll
    for (int i=0;i<8;++i)
      #pragma unroll
      for (int j=0;j<8;++j) h[i][j] += av[i]*bv[j];
  }
  #pragma unroll
  for (int i=0;i<8;++i)
    #pragma unroll
    for (int j=0;j<8;++j) h[i][j] += bb1v[j];

  // ---- LN stats: partials in bufB (W1T dead) ----
  __syncthreads();
  float* pts = bufB;              // [128][9]
  float* ptq = bufB + 1152;       // [128][9]
  float* stmu = bufB + 2304;      // [128]
  float* strs = bufB + 2432;      // [128]
  #pragma unroll
  for (int i=0;i<8;++i) {
    float ps=0.f, pq=0.f;
    #pragma unroll
    for (int j=0;j<8;++j) { ps += h[i][j]; pq += h[i][j]*h[i][j]; }
    pts[RI(i)*9 + ty] = ps;
    ptq[RI(i)*9 + ty] = pq;
  }
  __syncthreads();
  {
    float s=0.f, q=0.f;
    #pragma unroll
    for (int y=0;y<8;++y) { s += pts[tid*9+y]; q += ptq[tid*9+y]; }
    float mu = s*(1.f/64.f);
    float va = q*(1.f/64.f) - mu*mu;
    stmu[tid] = mu;
    strs[tid] = rsqrtf(va + EPSv);
  }
  __syncthreads();

  // ---- normalize + leaky, write HnT into bufA (E dead) ----
  {
    float muv[8], rsv[8];
    #pragma unroll
    for (int i=0;i<8;++i) { muv[i]=stmu[RI(i)]; rsv[i]=strs[RI(i)]; }
    #pragma unroll
    for (int i=0;i<8;++i)
      #pragma unroll
      for (int j=0;j<8;++j) {
        float hn = leaky(lngv[j]*(h[i][j]-muv[i])*rsv[i] + lnbv[j]);
        bufA[PJ(j)*128 + RI(i)] = hn;
      }
  }
  __syncthreads();

  // ---- GEMM2: g[r][q] = sum_p Hn[r][p]*Wb2[q][p] ----
  float gacc[8][8];
  #pragma unroll
  for (int i=0;i<8;++i)
    #pragma unroll
    for (int j=0;j<8;++j) gacc[i][j]=0.f;
  for (int p = 0; p < 64; ++p) {
    f4 al = *(const f4*)(bufA + p*128 + 4*tx);
    f4 ah = *(const f4*)(bufA + p*128 + 64 + 4*tx);
    f4 bl = *(const f4*)(bufC + p*64 + 4*ty);
    f4 bh = *(const f4*)(bufC + p*64 + 32 + 4*ty);
    float av[8] = {al[0],al[1],al[2],al[3],ah[0],ah[1],ah[2],ah[3]};
    float bv[8] = {bl[0],bl[1],bl[2],bl[3],bh[0],bh[1],bh[2],bh[3]};
    #pragma unroll
    for (int i=0;i<8;++i)
      #pragma unroll
      for (int j=0;j<8;++j) gacc[i][j] += av[i]*bv[j];
  }
  #pragma unroll
  for (int i=0;i<8;++i)
    #pragma unroll
    for (int j=0;j<8;++j) gacc[i][j] = leaky(gacc[i][j] + bb2v[j]);

  // ---- cumsum over s (per 64-row group) via 16-lane segment scan ----
  #pragma unroll
  for (int j=0;j<8;++j) {
    {
      float c0=gacc[0][j], c1=c0+gacc[1][j], c2=c1+gacc[2][j], c3=c2+gacc[3][j];
      float incl = c3;
      #pragma unroll
      for (int dd=1; dd<16; dd<<=1) {
        float t = __shfl_up(incl, dd, 16);
        if ((tid & 15) >= dd) incl += t;
      }
      float ex = incl - c3;
      gacc[0][j]=ex+c0; gacc[1][j]=ex+c1; gacc[2][j]=ex+c2; gacc[3][j]=ex+c3;
    }
    {
      float c0=gacc[4][j], c1=c0+gacc[5][j], c2=c1+gacc[6][j], c3=c2+gacc[7][j];
      float incl = c3;
      #pragma unroll
      for (int dd=1; dd<16; dd<<=1) {
        float t = __shfl_up(incl, dd, 16);
        if ((tid & 15) >= dd) incl += t;
      }
      float ex = incl - c3;
      gacc[4][j]=ex+c0; gacc[5][j]=ex+c1; gacc[6][j]=ex+c2; gacc[7][j]=ex+c3;
    }
  }
  __syncthreads();

  // ---- write AcmlT into bufA; stage WkT [64][40] into bufB ----
  #pragma unroll
  for (int i=0;i<8;++i)
    #pragma unroll
    for (int j=0;j<8;++j) bufA[PJ(j)*128 + RI(i)] = gacc[i][j];
  for (int i2 = tid; i2 < 2560; i2 += 128) {
    int q = i2/40, k = i2%40;
    bufB[i2] = (k < Dv) ? Wk[k*64 + q] : 0.f;
  }
  __syncthreads();

  // ---- GEMM3: u[r][k] = sum_q acml[r][q]*Wk[k][q] (k<38) ----
  float u[8][4], u2[8][4];
  #pragma unroll
  for (int i=0;i<8;++i)
    #pragma unroll
    for (int j=0;j<4;++j) { u[i][j]=0.f; u2[i][j]=0.f; }
  for (int q = 0; q < 64; ++q) {
    f4 al = *(const f4*)(bufA + q*128 + 4*tx);
    f4 ah = *(const f4*)(bufA + q*128 + 64 + 4*tx);
    f4 b1v = *(const f4*)(bufB + q*40 + 4*ty);
    float av[8] = {al[0],al[1],al[2],al[3],ah[0],ah[1],ah[2],ah[3]};
    #pragma unroll
    for (int i=0;i<8;++i)
      #pragma unroll
      for (int j=0;j<4;++j) u[i][j] += av[i]*b1v[j];
    if (ty < 2) {
      f4 b2v = *(const f4*)(bufB + q*40 + 32 + 4*ty);
      #pragma unroll
      for (int i=0;i<8;++i)
        #pragma unroll
        for (int j=0;j<4;++j) u2[i][j] += av[i]*b2v[j];
    }
  }

  // ---- epilogue: sigm(u+bk)*wq, reduce over k -> score1 ----
  const int b0g = bd0/Dv, d0g = bd0%Dv, b1g = bd1/Dv, d1g = bd1%Dv;
  float* pt2 = bufC;   // [128][9]
  #pragma unroll
  for (int i=0;i<8;++i) {
    int s = 4*tx + (i & 3);
    int bb_ = (i<4) ? b0g : b1g;
    const float* wqrow = wq2_ws + ((size_t)bb_*Sv + s)*Dv;
    float p = 0.f;
    #pragma unroll
    for (int j=0;j<4;++j) {
      int k = 4*ty + j;
      p += sigm(u[i][j] + bk[k]) * wqrow[k];
    }
    if (ty < 2) {
      #pragma unroll
      for (int j=0;j<4;++j) {
        int k = 32 + 4*ty + j;
        if (k < Dv) p += sigm(u2[i][j] + bk[k]) * wqrow[k];
      }
    }
    pt2[RI(i)*9 + ty] = p;
  }
  __syncthreads();
  {
    int rr = tid;                 // 0..127
    float tot = 0.f;
    #pragma unroll
    for (int y=0;y<8;++y) tot += pt2[rr*9+y];
    int grp = rr >> 6, s = rr & 63;
    int bb_ = grp ? b1g : b0g;
    int dd_ = grp ? d1g : d0g;
    score1[((size_t)bb_*Sv + s)*Dv + dd_] = tot;
  }
#undef RI
#undef PJ
}

// ---------------- K3: att1 softmax + contributes1/output1 + wq_a ----------------
__global__ __launch_bounds__(256) void k3_att1(
    const float* __restrict__ score1, const float* __restrict__ wv_ws,
    const float* __restrict__ e_ws, const float* __restrict__ Wq2, const float* __restrict__ bq2,
    float* __restrict__ out_c1, float* __restrict__ output1, float* __restrict__ wq_a)
{
  const int blk = blockIdx.x;
  const int b = blk / Sv, s = blk % Sv;
  const int tid = threadIdx.x;
  const int wid = tid>>6, lane = tid&63;
  __shared__ float red[4];

  if (wid==0) {
    const float invsq = 0.16222142113076254f; // 1/sqrt(38)
    float sc = (lane<Dv) ? score1[(b*Sv+s)*Dv+lane]*invsq : -1e30f;
    float mx = wmax64(sc);
    float ex = (lane<Dv) ? expf(sc-mx) : 0.f;
    float den = wred64(ex);
    float att = ex/den;
    float c1 = 0.f;
    if (lane<Dv) {
      c1 = wv_ws[(b*Dv+lane)*Sv+s]*att;
      out_c1[(b*Sv+s)*Dv+lane] = c1;
    }
    float tot = wred64(c1);
    if (lane==0) output1[b*Sv+s] = tot;
  }
  // wq_a[b,s] = sigmoid(ef[b,s]·Wq2 + bq2)
  float p = 0.f;
  for (int idx=tid; idx<Dv*64; idx+=256) {
    int d = idx>>6, o = idx&63;
    p += e_ws[((size_t)(b*Dv+d)*Sv+s)*64+o]*Wq2[idx];
  }
  p = wred64(p);
  if (lane==0) red[wid]=p;
  __syncthreads();
  if (tid==0) wq_a[b*Sv+s] = sigm(red[0]+red[1]+red[2]+red[3]+bq2[0]);
}

// ---------------- K4: per-b 64x64x2432 GEMM + fused score2 ----------------
// grid 256, 256 threads, 4x4 per-thread tiles, K-chunks of 64 (d=0..37).
__global__ __launch_bounds__(256) void k4_gemm(
    const float* __restrict__ e_ws, const float* __restrict__ Wk2, const float* __restrict__ bk2,
    const float* __restrict__ wq_a, float* __restrict__ score2)
{
  const int b = blockIdx.x;
  const int tid = threadIdx.x;
  const int tx = tid & 15, ty = tid >> 4;       // tile coords
  __shared__ float AsT[64*68];
  __shared__ float BsT[64*68];
  __shared__ float pt[64*17];

  float acc[4][4];
  #pragma unroll
  for (int i=0;i<4;++i)
    #pragma unroll
    for (int j=0;j<4;++j) acc[i][j]=0.f;

  const int r0 = tid & 15, oc0 = tid >> 4;      // staging map
  const f4* Bsrc = (const f4*)Wk2;              // row stride 608 f4

  for (int d = 0; d < 38; ++d) {
    const f4* Asrc = (const f4*)(e_ws + ((size_t)(b*Dv+d))*4096);
    #pragma unroll
    for (int q = 0; q < 4; ++q) {
      int r = r0 + 16*q;
      f4 av = Asrc[r*16 + oc0];
      f4 bv = Bsrc[(size_t)r*608 + d*16 + oc0];
      #pragma unroll
      for (int k = 0; k < 4; ++k) {
        AsT[(4*oc0+k)*68 + r] = av[k];
        BsT[(4*oc0+k)*68 + r] = bv[k];
      }
    }
    __syncthreads();
    #pragma unroll 4
    for (int o = 0; o < 64; ++o) {
      f4 a  = *(const f4*)&AsT[o*68 + 4*tx];
      f4 bb = *(const f4*)&BsT[o*68 + 4*ty];
      #pragma unroll
      for (int i=0;i<4;++i)
        #pragma unroll
        for (int j=0;j<4;++j) acc[i][j] += a[i]*bb[j];
    }
    __syncthreads();
  }

  // epilogue: score2[b,t] = sum_s sigm(C[t,s]+bk2[s])*wq_a[b,s]
  #pragma unroll
  for (int i=0;i<4;++i) {
    float p = 0.f;
    #pragma unroll
    for (int j=0;j<4;++j) {
      int s = 4*ty + j;
      p += sigm(acc[i][j] + bk2[s]) * wq_a[b*Sv + s];
    }
    pt[(4*tx+i)*17 + ty] = p;
  }
  __syncthreads();
  if (tid < 64) {
    float tot = 0.f;
    #pragma unroll
    for (int y=0;y<16;++y) tot += pt[tid*17+y];
    score2[b*Sv + tid] = tot;
  }
}

// ---------------- K5: att2 softmax + contributes2/output2 ----------------
__global__ __launch_bounds__(64) void k5_final(
    const float* __restrict__ score2, const float* __restrict__ output1,
    float* __restrict__ out)
{
  const int b = blockIdx.x;
  const int lane = threadIdx.x;
  const float inv = 0.039528470752104741f; // 1/sqrt(640)
  float v = score2[b*Sv+lane]*inv;
  float mx = wmax64(v);
  float ex = expf(v-mx);
  float den = wred64(ex);
  float att = ex/den;
  float c2 = output1[b*Sv+lane]*att;
  out[256 + b*Sv + lane] = c2;     // contributes2
  float tot = wred64(c2);
  if (lane==0) out[b] = tot;       // output2
}

extern "C" void kernel_launch(void* const* d_in, const int* in_sizes, int n_in,
                              void* d_out, int out_size, void* d_ws, size_t ws_size,
                              hipStream_t stream)
{
  const float* x    = (const float*)d_in[0];
  const float* W1   = (const float*)d_in[1];
  const float* b1   = (const float*)d_in[2];
  const float* W2   = (const float*)d_in[3];
  const float* b2   = (const float*)d_in[4];
  const float* Wl   = (const float*)d_in[5];
  const float* bl   = (const float*)d_in[6];
  const float* Wb1  = (const float*)d_in[7];
  const float* bb1  = (const float*)d_in[8];
  const float* lng  = (const float*)d_in[9];
  const float* lnb  = (const float*)d_in[10];
  const float* Wb2  = (const float*)d_in[11];
  const float* bb2  = (const float*)d_in[12];
  const float* Wq   = (const float*)d_in[13];
  const float* bq   = (const float*)d_in[14];
  const float* Wk   = (const float*)d_in[15];
  const float* bk   = (const float*)d_in[16];
  const float* Wv1  = (const float*)d_in[17];
  const float* bv1  = (const float*)d_in[18];
  const float* lnvg = (const float*)d_in[19];
  const float* lnvb = (const float*)d_in[20];
  const float* Wv2  = (const float*)d_in[21];
  const float* bv2  = (const float*)d_in[22];
  const float* Wq2  = (const float*)d_in[23];
  const float* bq2  = (const float*)d_in[24];
  const float* Wk2  = (const float*)d_in[25];
  const float* bk2  = (const float*)d_in[26];

  float* ws = (float*)d_ws;
  float* e_ws  = ws;                                   // B*D*S*64
  float* wq2w  = e_ws + (size_t)Bv*Dv*Sv*64;           // B*S*D  ([b][s][k])
  float* wv_ws = wq2w + (size_t)Bv*Sv*Dv;              // B*D*S
  float* sc1   = wv_ws + (size_t)Bv*Dv*Sv;             // B*S*D
  float* out1  = sc1 + (size_t)Bv*Sv*Dv;               // B*S
  float* wqa   = out1 + (size_t)Bv*Sv;                 // B*S
  float* sc2   = wqa + (size_t)Bv*Sv;                  // B*S

  float* out = (float*)d_out;
  float* out_c1 = out + 256 + Bv*Sv;                   // contributes1 offset

  hipLaunchKernelGGL(k1_fe, dim3(Bv*Dv), dim3(256), 0, stream,
    x, W1, b1, W2, b2, Wl, bl, Wq, bq, Wv1, bv1, lnvg, lnvb, Wv2, bv2,
    e_ws, wq2w, wv_ws);
  hipLaunchKernelGGL(k2_fused, dim3(Bv*Dv/2), dim3(128), 0, stream,
    e_ws, Wb1, bb1, lng, lnb, Wb2, bb2, Wk, bk, wq2w, sc1);
  hipLaunchKernelGGL(k3_att1, dim3(Bv*Sv), dim3(256), 0, stream,
    sc1, wv_ws, e_ws, Wq2, bq2, out_c1, out1, wqa);
  hipLaunchKernelGGL(k4_gemm, dim3(Bv), dim3(256), 0, stream,
    e_ws, Wk2, bk2, wqa, sc2);
  hipLaunchKernelGGL(k5_final, dim3(Bv), dim3(64), 0, stream, sc2, out1, out);
}

// Round 3
// 1191.548 us; speedup vs baseline: 2.4196x; 1.3079x over previous
//
#include <hip/hip_runtime.h>
#include <math.h>

#define Bv 256
#define Dv 38
#define Sv 64
#define SWv 10
#define EPSv 1e-5f

typedef float f4 __attribute__((ext_vector_type(4)));

__device__ __forceinline__ float leaky(float v){ return v > 0.f ? v : 0.01f*v; }
__device__ __forceinline__ float sigm(float v){ return 1.f/(1.f+expf(-v)); }

__device__ __forceinline__ float wred64(float v){
  #pragma unroll
  for (int off=32; off; off>>=1) v += __shfl_xor(v, off, 64);
  return v;
}
__device__ __forceinline__ float wmax64(float v){
  #pragma unroll
  for (int off=32; off; off>>=1) v = fmaxf(v, __shfl_xor(v, off, 64));
  return v;
}

// ---------------- K1: FE1 + conv/pool + embed + wq + v/wv, register-tiled ----------------
// One (b,d) per block, 128 threads (tx 0..15 -> 4 s-rows, ty 0..7 -> 8/4 cols).
// LDS map (floats):
//   [0..4096)      f1T[t=64][s=64]        -> later eT[o=64][s=64]
//   [4096..6272)   WlT_c[q=32][68]        -> later Wv1T[o=64][36] (4096..6400)
//   [6272..8448)   mTc[q=32][68]          -> later pts@6400 ptq@6976 stats@7552 wqp@7680
//   [8448..9128)   W1T[w=10][68]
//   [9128..9808)   AT[w=10][68]
//   [9808..10144)  consts: b1@9808 bl@9872 Wq@9936 W2@10000 b2@10012 bv1@10016
//                  lnvg@10048 lnvb@10080 Wv2@10112
__global__ __launch_bounds__(128) void k1_fe2(
    const float* __restrict__ x, const float* __restrict__ W1, const float* __restrict__ b1,
    const float* __restrict__ W2, const float* __restrict__ b2,
    const float* __restrict__ Wl, const float* __restrict__ bl,
    const float* __restrict__ Wq, const float* __restrict__ bq,
    const float* __restrict__ Wv1, const float* __restrict__ bv1,
    const float* __restrict__ lnvg, const float* __restrict__ lnvb,
    const float* __restrict__ Wv2, const float* __restrict__ bv2,
    float* __restrict__ e_ws, float* __restrict__ wq2_ws, float* __restrict__ wv_ws)
{
  __shared__ float sm[10160];
  const int d = blockIdx.x >> 8;
  const int b = blockIdx.x & 255;
  const int tid = threadIdx.x;
  const int tx = tid & 15, ty = tid >> 4;   // ty 0..7
  const int bd = b*Dv + d;

#define PJ(j) ((j) < 4 ? 4*ty + (j) : 32 + 4*ty + ((j)-4))

  // ---- stage consts ----
  if (tid < 64) {
    sm[9808 + tid] = b1[d*64 + tid];
    sm[9872 + tid] = bl[d*64 + tid];
    sm[9936 + tid] = Wq[tid];
  } else {
    int t = tid - 64;
    if (t < 32) {
      sm[10016 + t] = bv1[d*32 + t];
      sm[10048 + t] = lnvg[d*32 + t];
      sm[10080 + t] = lnvb[d*32 + t];
      sm[10112 + t] = Wv2[d*32 + t];
    } else {
      int u = t - 32;
      if (u < 12) sm[10000 + u] = W2[d*12 + u];
      else if (u < 16) sm[10012 + (u-12)] = b2[d*4 + (u-12)];
    }
  }
  // ---- stage W1T[w][o], AT[w][s] ----
  for (int idx = tid; idx < 640; idx += 128) {
    int o = idx / 10, w = idx % 10;
    sm[8448 + w*68 + o] = W1[d*640 + idx];
  }
  {
    const float* xg = x + (size_t)bd * 640;
    for (int t = tid; t < 640; t += 128) {
      int s = t / 10, w = t % 10;
      sm[9128 + w*68 + s] = xg[t];
    }
  }
  __syncthreads();

  // ---- FE1 GEMM: f1[s][o], K=10 ----
  float fe[4][8];
  #pragma unroll
  for (int i=0;i<4;++i)
    #pragma unroll
    for (int j=0;j<8;++j) fe[i][j]=0.f;
  #pragma unroll
  for (int w = 0; w < 10; ++w) {
    f4 a   = *(const f4*)&sm[9128 + w*68 + 4*tx];
    f4 bl_ = *(const f4*)&sm[8448 + w*68 + 4*ty];
    f4 bh_ = *(const f4*)&sm[8448 + w*68 + 32 + 4*ty];
    float bv8[8] = {bl_[0],bl_[1],bl_[2],bl_[3],bh_[0],bh_[1],bh_[2],bh_[3]};
    #pragma unroll
    for (int i=0;i<4;++i)
      #pragma unroll
      for (int j=0;j<8;++j) fe[i][j] += a[i]*bv8[j];
  }
  // write f1T[o][s] (post-bias leaky)
  #pragma unroll
  for (int i=0;i<4;++i)
    #pragma unroll
    for (int j=0;j<8;++j) {
      int o = PJ(j);
      sm[o*64 + 4*tx + i] = leaky(fe[i][j] + sm[9808 + o]);
    }
  __syncthreads();

  // ---- embed: 4 K-chunks of conv/pool + GEMM ----
  float ea[4][8];
  #pragma unroll
  for (int i=0;i<4;++i)
    #pragma unroll
    for (int j=0;j<8;++j) ea[i][j]=0.f;

  for (int c = 0; c < 4; ++c) {
    // stage WlT_c[q][o]: q = ch*8+io <-> f = ch*31 + 8c + io (zero-fill invalid)
    {
      int lane = tid & 63, wv = tid >> 6;
      for (int q = wv; q < 32; q += 2) {
        int ch = q >> 3, io = q & 7;
        int ii = 8*c + io;
        float v = 0.f;
        if (ii <= 30) v = Wl[d*7936 + lane*124 + ch*31 + ii];
        sm[4096 + q*68 + lane] = v;
      }
    }
    // conv+pool chunk -> mTc[q][s]
    {
      int s = tid & 63, ioh = tid >> 6;
      #pragma unroll
      for (int it = 0; it < 4; ++it) {
        int io = ioh*4 + it;
        int i = 8*c + io;
        if (i <= 30) {
          int t0 = 2*i - 1;
          float v0 = (t0 < 0) ? 0.f : sm[t0*64 + s];
          float v1 = sm[(t0+1)*64 + s];
          float v2 = sm[(t0+2)*64 + s];
          float v3 = sm[(t0+3)*64 + s];
          float v4 = sm[(t0+4)*64 + s];
          #pragma unroll
          for (int ch = 0; ch < 4; ++ch) {
            float w0 = sm[10000+ch*3], w1 = sm[10000+ch*3+1], w2 = sm[10000+ch*3+2];
            float bb = sm[10012+ch];
            float ca = bb + v0*w0 + v1*w1 + v2*w2;
            float cb_ = bb + v1*w0 + v2*w1 + v3*w2;
            float cc = bb + v2*w0 + v3*w1 + v4*w2;
            float mx = fmaxf(fmaxf(leaky(ca), leaky(cb_)), leaky(cc));
            sm[6272 + (ch*8+io)*68 + s] = mx;
          }
        }
      }
    }
    __syncthreads();
    // GEMM chunk: K=32 (invalid rows are zero in WlT_c)
    #pragma unroll 8
    for (int q = 0; q < 32; ++q) {
      f4 a   = *(const f4*)&sm[6272 + q*68 + 4*tx];
      f4 bl_ = *(const f4*)&sm[4096 + q*68 + 4*ty];
      f4 bh_ = *(const f4*)&sm[4096 + q*68 + 32 + 4*ty];
      float bv8[8] = {bl_[0],bl_[1],bl_[2],bl_[3],bh_[0],bh_[1],bh_[2],bh_[3]};
      #pragma unroll
      for (int i=0;i<4;++i)
        #pragma unroll
        for (int j=0;j<8;++j) ea[i][j] += a[i]*bv8[j];
    }
    __syncthreads();
  }

  // ---- e final: bias + leaky; write e_ws, eT, wq partials; stage Wv1T ----
  float ev[4][8];
  #pragma unroll
  for (int i=0;i<4;++i)
    #pragma unroll
    for (int j=0;j<8;++j) ev[i][j] = leaky(ea[i][j] + sm[9872 + PJ(j)]);

  {
    float* erow = e_ws + (size_t)bd * 4096;
    #pragma unroll
    for (int i=0;i<4;++i) {
      f4 lo = {ev[i][0],ev[i][1],ev[i][2],ev[i][3]};
      f4 hi = {ev[i][4],ev[i][5],ev[i][6],ev[i][7]};
      *(f4*)&erow[(4*tx+i)*64 + 4*ty] = lo;
      *(f4*)&erow[(4*tx+i)*64 + 32 + 4*ty] = hi;
    }
  }
  #pragma unroll
  for (int i=0;i<4;++i)
    #pragma unroll
    for (int j=0;j<8;++j) sm[PJ(j)*64 + 4*tx + i] = ev[i][j];   // eT over f1T
  #pragma unroll
  for (int i=0;i<4;++i) {
    float p = 0.f;
    #pragma unroll
    for (int j=0;j<8;++j) p += ev[i][j]*sm[9936 + PJ(j)];
    sm[7680 + (4*tx+i)*9 + ty] = p;                              // wq partials
  }
  for (int idx = tid; idx < 2048; idx += 128) {                  // Wv1T[o][h]
    int h = idx >> 6, o = idx & 63;
    sm[4096 + o*36 + h] = Wv1[d*2048 + idx];
  }
  __syncthreads();

  // ---- v-GEMM: v[s][h] = sum_o e[s][o]*Wv1[h][o], K=64 ----
  float va[4][4];
  #pragma unroll
  for (int i=0;i<4;++i)
    #pragma unroll
    for (int j=0;j<4;++j) va[i][j]=0.f;
  #pragma unroll 8
  for (int o = 0; o < 64; ++o) {
    f4 a  = *(const f4*)&sm[o*64 + 4*tx];
    f4 bb = *(const f4*)&sm[4096 + o*36 + 4*ty];
    #pragma unroll
    for (int i=0;i<4;++i)
      #pragma unroll
      for (int j=0;j<4;++j) va[i][j] += a[i]*bb[j];
  }
  #pragma unroll
  for (int i=0;i<4;++i)
    #pragma unroll
    for (int j=0;j<4;++j) va[i][j] += sm[10016 + 4*ty + j];

  // LN partials
  #pragma unroll
  for (int i=0;i<4;++i) {
    float ps=0.f, pq=0.f;
    #pragma unroll
    for (int j=0;j<4;++j) { ps += va[i][j]; pq += va[i][j]*va[i][j]; }
    sm[6400 + (4*tx+i)*9 + ty] = ps;
    sm[6976 + (4*tx+i)*9 + ty] = pq;
  }
  __syncthreads();
  if (tid < 64) {
    float s_=0.f, q_=0.f;
    #pragma unroll
    for (int y=0;y<8;++y) { s_ += sm[6400 + tid*9 + y]; q_ += sm[6976 + tid*9 + y]; }
    float mu = s_*(1.f/32.f);
    float vr = q_*(1.f/32.f) - mu*mu;
    sm[7552 + tid] = mu;
    sm[7616 + tid] = rsqrtf(vr + EPSv);
    // wq reduce (partials @7680, untouched)
    float p = 0.f;
    #pragma unroll
    for (int y=0;y<8;++y) p += sm[7680 + tid*9 + y];
    wq2_ws[((size_t)b*64 + tid)*Dv + d] = sigm(p + bq[0]);
  }
  __syncthreads();
  #pragma unroll
  for (int i=0;i<4;++i) {
    float mu = sm[7552 + 4*tx + i];
    float rs = sm[7616 + 4*tx + i];
    float p = 0.f;
    #pragma unroll
    for (int j=0;j<4;++j) {
      int h = 4*ty + j;
      float vh = leaky(sm[10048+h]*(va[i][j]-mu)*rs + sm[10080+h]);
      p += vh*sm[10112+h];
    }
    sm[6400 + (4*tx+i)*9 + ty] = p;
  }
  __syncthreads();
  if (tid < 64) {
    float p = 0.f;
    #pragma unroll
    for (int y=0;y<8;++y) p += sm[6400 + tid*9 + y];
    wv_ws[(size_t)bd*64 + tid] = fmaxf(p + bv2[d], 0.f);
  }
#undef PJ
}

// ---------------- K2: fused Wb1+LN+Wb2+cumsum+Wk/wq -> score1 ----------------
__global__ __launch_bounds__(128) void k2_fused(
    const float* __restrict__ e_ws,
    const float* __restrict__ Wb1, const float* __restrict__ bb1,
    const float* __restrict__ lng, const float* __restrict__ lnb,
    const float* __restrict__ Wb2, const float* __restrict__ bb2,
    const float* __restrict__ Wk, const float* __restrict__ bk,
    const float* __restrict__ wq2_ws, float* __restrict__ score1)
{
  __shared__ float smem[16384];           // 64 KiB, phase-aliased
  float* bufA = smem;                     // 8192 f  [64][128]: EsT -> HnT -> AcmlT
  float* bufB = smem + 8192;              // 4096 f  [64][64]:  W1T -> pts/ptq/stats -> WkT[64][40]
  float* bufC = smem + 12288;             // 4096 f  [64][64]:  W2T -> pt2[128][9]

  const int tid = threadIdx.x;
  const int tx = tid & 15;
  const int ty = tid >> 4;                // 0..7
  const int bd0 = blockIdx.x * 2;
  const int bd1 = bd0 + 1;

#define RI(i) ((i) < 4 ? 4*tx + (i) : 64 + 4*tx + ((i)-4))
#define PJ(j) ((j) < 4 ? 4*ty + (j) : 32 + 4*ty + ((j)-4))

  // ---- stage EsT (bufA), W1T (bufB), W2T (bufC), transposed ----
  {
    const int r0 = tid & 15, c0 = tid >> 4;      // c0 0..7
    const f4* Esrc  = (const f4*)(e_ws + (size_t)bd0 * 4096);
    #pragma unroll
    for (int p = 0; p < 2; ++p) {
      int oc = c0 + 8*p;
      #pragma unroll
      for (int q = 0; q < 8; ++q) {
        int r = r0 + 16*q;
        f4 v = Esrc[r*16 + oc];
        #pragma unroll
        for (int k = 0; k < 4; ++k) bufA[(4*oc+k)*128 + r] = v[k];
      }
    }
    const f4* W1src = (const f4*)Wb1;
    const f4* W2src = (const f4*)Wb2;
    #pragma unroll
    for (int p = 0; p < 2; ++p) {
      int oc = c0 + 8*p;
      #pragma unroll
      for (int q = 0; q < 4; ++q) {
        int rr = r0 + 16*q;
        f4 v1 = W1src[rr*16 + oc];
        f4 v2 = W2src[rr*16 + oc];
        #pragma unroll
        for (int k = 0; k < 4; ++k) {
          bufB[(4*oc+k)*64 + rr] = v1[k];
          bufC[(4*oc+k)*64 + rr] = v2[k];
        }
      }
    }
  }
  __syncthreads();

  // per-thread column constants
  float bb1v[8], lngv[8], lnbv[8], bb2v[8];
  #pragma unroll
  for (int j=0;j<8;++j) {
    int p = PJ(j);
    bb1v[j]=bb1[p]; lngv[j]=lng[p]; lnbv[j]=lnb[p]; bb2v[j]=bb2[p];
  }

  // ---- GEMM1: h[r][p] = sum_o E[r][o]*Wb1[p][o] ----
  float h[8][8];
  #pragma unroll
  for (int i=0;i<8;++i)
    #pragma unroll
    for (int j=0;j<8;++j) h[i][j]=0.f;
  for (int o = 0; o < 64; ++o) {
    f4 al = *(const f4*)(bufA + o*128 + 4*tx);
    f4 ah = *(const f4*)(bufA + o*128 + 64 + 4*tx);
    f4 bl = *(const f4*)(bufB + o*64 + 4*ty);
    f4 bh = *(const f4*)(bufB + o*64 + 32 + 4*ty);
    float av[8] = {al[0],al[1],al[2],al[3],ah[0],ah[1],ah[2],ah[3]};
    float bv[8] = {bl[0],bl[1],bl[2],bl[3],bh[0],bh[1],bh[2],bh[3]};
    #pragma unroll
    for (int i=0;i<8;++i)
      #pragma unroll
      for (int j=0;j<8;++j) h[i][j] += av[i]*bv[j];
  }
  #pragma unroll
  for (int i=0;i<8;++i)
    #pragma unroll
    for (int j=0;j<8;++j) h[i][j] += bb1v[j];

  // ---- LN stats: partials in bufB (W1T dead) ----
  __syncthreads();
  float* pts = bufB;              // [128][9]
  float* ptq = bufB + 1152;       // [128][9]
  float* stmu = bufB + 2304;      // [128]
  float* strs = bufB + 2432;      // [128]
  #pragma unroll
  for (int i=0;i<8;++i) {
    float ps=0.f, pq=0.f;
    #pragma unroll
    for (int j=0;j<8;++j) { ps += h[i][j]; pq += h[i][j]*h[i][j]; }
    pts[RI(i)*9 + ty] = ps;
    ptq[RI(i)*9 + ty] = pq;
  }
  __syncthreads();
  {
    float s=0.f, q=0.f;
    #pragma unroll
    for (int y=0;y<8;++y) { s += pts[tid*9+y]; q += ptq[tid*9+y]; }
    float mu = s*(1.f/64.f);
    float va = q*(1.f/64.f) - mu*mu;
    stmu[tid] = mu;
    strs[tid] = rsqrtf(va + EPSv);
  }
  __syncthreads();

  // ---- normalize + leaky, write HnT into bufA (E dead) ----
  {
    float muv[8], rsv[8];
    #pragma unroll
    for (int i=0;i<8;++i) { muv[i]=stmu[RI(i)]; rsv[i]=strs[RI(i)]; }
    #pragma unroll
    for (int i=0;i<8;++i)
      #pragma unroll
      for (int j=0;j<8;++j) {
        float hn = leaky(lngv[j]*(h[i][j]-muv[i])*rsv[i] + lnbv[j]);
        bufA[PJ(j)*128 + RI(i)] = hn;
      }
  }
  __syncthreads();

  // ---- GEMM2: g[r][q] = sum_p Hn[r][p]*Wb2[q][p] ----
  float gacc[8][8];
  #pragma unroll
  for (int i=0;i<8;++i)
    #pragma unroll
    for (int j=0;j<8;++j) gacc[i][j]=0.f;
  for (int p = 0; p < 64; ++p) {
    f4 al = *(const f4*)(bufA + p*128 + 4*tx);
    f4 ah = *(const f4*)(bufA + p*128 + 64 + 4*tx);
    f4 bl = *(const f4*)(bufC + p*64 + 4*ty);
    f4 bh = *(const f4*)(bufC + p*64 + 32 + 4*ty);
    float av[8] = {al[0],al[1],al[2],al[3],ah[0],ah[1],ah[2],ah[3]};
    float bv[8] = {bl[0],bl[1],bl[2],bl[3],bh[0],bh[1],bh[2],bh[3]};
    #pragma unroll
    for (int i=0;i<8;++i)
      #pragma unroll
      for (int j=0;j<8;++j) gacc[i][j] += av[i]*bv[j];
  }
  #pragma unroll
  for (int i=0;i<8;++i)
    #pragma unroll
    for (int j=0;j<8;++j) gacc[i][j] = leaky(gacc[i][j] + bb2v[j]);

  // ---- cumsum over s (per 64-row group) via 16-lane segment scan ----
  #pragma unroll
  for (int j=0;j<8;++j) {
    {
      float c0=gacc[0][j], c1=c0+gacc[1][j], c2=c1+gacc[2][j], c3=c2+gacc[3][j];
      float incl = c3;
      #pragma unroll
      for (int dd=1; dd<16; dd<<=1) {
        float t = __shfl_up(incl, dd, 16);
        if ((tid & 15) >= dd) incl += t;
      }
      float ex = incl - c3;
      gacc[0][j]=ex+c0; gacc[1][j]=ex+c1; gacc[2][j]=ex+c2; gacc[3][j]=ex+c3;
    }
    {
      float c0=gacc[4][j], c1=c0+gacc[5][j], c2=c1+gacc[6][j], c3=c2+gacc[7][j];
      float incl = c3;
      #pragma unroll
      for (int dd=1; dd<16; dd<<=1) {
        float t = __shfl_up(incl, dd, 16);
        if ((tid & 15) >= dd) incl += t;
      }
      float ex = incl - c3;
      gacc[4][j]=ex+c0; gacc[5][j]=ex+c1; gacc[6][j]=ex+c2; gacc[7][j]=ex+c3;
    }
  }
  __syncthreads();

  // ---- write AcmlT into bufA; stage WkT [64][40] into bufB ----
  #pragma unroll
  for (int i=0;i<8;++i)
    #pragma unroll
    for (int j=0;j<8;++j) bufA[PJ(j)*128 + RI(i)] = gacc[i][j];
  for (int i2 = tid; i2 < 2560; i2 += 128) {
    int q = i2/40, k = i2%40;
    bufB[i2] = (k < Dv) ? Wk[k*64 + q] : 0.f;
  }
  __syncthreads();

  // ---- GEMM3: u[r][k] = sum_q acml[r][q]*Wk[k][q] (k<38) ----
  float u[8][4], u2[8][4];
  #pragma unroll
  for (int i=0;i<8;++i)
    #pragma unroll
    for (int j=0;j<4;++j) { u[i][j]=0.f; u2[i][j]=0.f; }
  for (int q = 0; q < 64; ++q) {
    f4 al = *(const f4*)(bufA + q*128 + 4*tx);
    f4 ah = *(const f4*)(bufA + q*128 + 64 + 4*tx);
    f4 b1v = *(const f4*)(bufB + q*40 + 4*ty);
    float av[8] = {al[0],al[1],al[2],al[3],ah[0],ah[1],ah[2],ah[3]};
    #pragma unroll
    for (int i=0;i<8;++i)
      #pragma unroll
      for (int j=0;j<4;++j) u[i][j] += av[i]*b1v[j];
    if (ty < 2) {
      f4 b2v = *(const f4*)(bufB + q*40 + 32 + 4*ty);
      #pragma unroll
      for (int i=0;i<8;++i)
        #pragma unroll
        for (int j=0;j<4;++j) u2[i][j] += av[i]*b2v[j];
    }
  }

  // ---- epilogue: sigm(u+bk)*wq, reduce over k -> score1 ----
  const int b0g = bd0/Dv, d0g = bd0%Dv, b1g = bd1/Dv, d1g = bd1%Dv;
  float* pt2 = bufC;   // [128][9]
  #pragma unroll
  for (int i=0;i<8;++i) {
    int s = 4*tx + (i & 3);
    int bb_ = (i<4) ? b0g : b1g;
    const float* wqrow = wq2_ws + ((size_t)bb_*Sv + s)*Dv;
    float p = 0.f;
    #pragma unroll
    for (int j=0;j<4;++j) {
      int k = 4*ty + j;
      p += sigm(u[i][j] + bk[k]) * wqrow[k];
    }
    if (ty < 2) {
      #pragma unroll
      for (int j=0;j<4;++j) {
        int k = 32 + 4*ty + j;
        if (k < Dv) p += sigm(u2[i][j] + bk[k]) * wqrow[k];
      }
    }
    pt2[RI(i)*9 + ty] = p;
  }
  __syncthreads();
  {
    int rr = tid;                 // 0..127
    float tot = 0.f;
    #pragma unroll
    for (int y=0;y<8;++y) tot += pt2[rr*9+y];
    int grp = rr >> 6, s = rr & 63;
    int bb_ = grp ? b1g : b0g;
    int dd_ = grp ? d1g : d0g;
    score1[((size_t)bb_*Sv + s)*Dv + dd_] = tot;
  }
#undef RI
#undef PJ
}

// ---------------- K3: att1 softmax + contributes1/output1 + wq_a ----------------
__global__ __launch_bounds__(256) void k3_att1(
    const float* __restrict__ score1, const float* __restrict__ wv_ws,
    const float* __restrict__ e_ws, const float* __restrict__ Wq2, const float* __restrict__ bq2,
    float* __restrict__ out_c1, float* __restrict__ output1, float* __restrict__ wq_a)
{
  const int blk = blockIdx.x;
  const int b = blk / Sv, s = blk % Sv;
  const int tid = threadIdx.x;
  const int wid = tid>>6, lane = tid&63;
  __shared__ float red[4];

  if (wid==0) {
    const float invsq = 0.16222142113076254f; // 1/sqrt(38)
    float sc = (lane<Dv) ? score1[(b*Sv+s)*Dv+lane]*invsq : -1e30f;
    float mx = wmax64(sc);
    float ex = (lane<Dv) ? expf(sc-mx) : 0.f;
    float den = wred64(ex);
    float att = ex/den;
    float c1 = 0.f;
    if (lane<Dv) {
      c1 = wv_ws[(b*Dv+lane)*Sv+s]*att;
      out_c1[(b*Sv+s)*Dv+lane] = c1;
    }
    float tot = wred64(c1);
    if (lane==0) output1[b*Sv+s] = tot;
  }
  // wq_a[b,s] = sigmoid(ef[b,s]·Wq2 + bq2)
  float p = 0.f;
  for (int idx=tid; idx<Dv*64; idx+=256) {
    int d = idx>>6, o = idx&63;
    p += e_ws[((size_t)(b*Dv+d)*Sv+s)*64+o]*Wq2[idx];
  }
  p = wred64(p);
  if (lane==0) red[wid]=p;
  __syncthreads();
  if (tid==0) wq_a[b*Sv+s] = sigm(red[0]+red[1]+red[2]+red[3]+bq2[0]);
}

// ---------------- K4: per-b 64x64x2432 GEMM + fused score2 ----------------
__global__ __launch_bounds__(256) void k4_gemm(
    const float* __restrict__ e_ws, const float* __restrict__ Wk2, const float* __restrict__ bk2,
    const float* __restrict__ wq_a, float* __restrict__ score2)
{
  const int b = blockIdx.x;
  const int tid = threadIdx.x;
  const int tx = tid & 15, ty = tid >> 4;       // tile coords
  __shared__ float AsT[64*68];
  __shared__ float BsT[64*68];
  __shared__ float pt[64*17];

  float acc[4][4];
  #pragma unroll
  for (int i=0;i<4;++i)
    #pragma unroll
    for (int j=0;j<4;++j) acc[i][j]=0.f;

  const int r0 = tid & 15, oc0 = tid >> 4;      // staging map
  const f4* Bsrc = (const f4*)Wk2;              // row stride 608 f4

  for (int d = 0; d < 38; ++d) {
    const f4* Asrc = (const f4*)(e_ws + ((size_t)(b*Dv+d))*4096);
    #pragma unroll
    for (int q = 0; q < 4; ++q) {
      int r = r0 + 16*q;
      f4 av = Asrc[r*16 + oc0];
      f4 bv = Bsrc[(size_t)r*608 + d*16 + oc0];
      #pragma unroll
      for (int k = 0; k < 4; ++k) {
        AsT[(4*oc0+k)*68 + r] = av[k];
        BsT[(4*oc0+k)*68 + r] = bv[k];
      }
    }
    __syncthreads();
    #pragma unroll 4
    for (int o = 0; o < 64; ++o) {
      f4 a  = *(const f4*)&AsT[o*68 + 4*tx];
      f4 bb = *(const f4*)&BsT[o*68 + 4*ty];
      #pragma unroll
      for (int i=0;i<4;++i)
        #pragma unroll
        for (int j=0;j<4;++j) acc[i][j] += a[i]*bb[j];
    }
    __syncthreads();
  }

  // epilogue: score2[b,t] = sum_s sigm(C[t,s]+bk2[s])*wq_a[b,s]
  #pragma unroll
  for (int i=0;i<4;++i) {
    float p = 0.f;
    #pragma unroll
    for (int j=0;j<4;++j) {
      int s = 4*ty + j;
      p += sigm(acc[i][j] + bk2[s]) * wq_a[b*Sv + s];
    }
    pt[(4*tx+i)*17 + ty] = p;
  }
  __syncthreads();
  if (tid < 64) {
    float tot = 0.f;
    #pragma unroll
    for (int y=0;y<16;++y) tot += pt[tid*17+y];
    score2[b*Sv + tid] = tot;
  }
}

// ---------------- K5: att2 softmax + contributes2/output2 ----------------
__global__ __launch_bounds__(64) void k5_final(
    const float* __restrict__ score2, const float* __restrict__ output1,
    float* __restrict__ out)
{
  const int b = blockIdx.x;
  const int lane = threadIdx.x;
  const float inv = 0.039528470752104741f; // 1/sqrt(640)
  float v = score2[b*Sv+lane]*inv;
  float mx = wmax64(v);
  float ex = expf(v-mx);
  float den = wred64(ex);
  float att = ex/den;
  float c2 = output1[b*Sv+lane]*att;
  out[256 + b*Sv + lane] = c2;     // contributes2
  float tot = wred64(c2);
  if (lane==0) out[b] = tot;       // output2
}

extern "C" void kernel_launch(void* const* d_in, const int* in_sizes, int n_in,
                              void* d_out, int out_size, void* d_ws, size_t ws_size,
                              hipStream_t stream)
{
  const float* x    = (const float*)d_in[0];
  const float* W1   = (const float*)d_in[1];
  const float* b1   = (const float*)d_in[2];
  const float* W2   = (const float*)d_in[3];
  const float* b2   = (const float*)d_in[4];
  const float* Wl   = (const float*)d_in[5];
  const float* bl   = (const float*)d_in[6];
  const float* Wb1  = (const float*)d_in[7];
  const float* bb1  = (const float*)d_in[8];
  const float* lng  = (const float*)d_in[9];
  const float* lnb  = (const float*)d_in[10];
  const float* Wb2  = (const float*)d_in[11];
  const float* bb2  = (const float*)d_in[12];
  const float* Wq   = (const float*)d_in[13];
  const float* bq   = (const float*)d_in[14];
  const float* Wk   = (const float*)d_in[15];
  const float* bk   = (const float*)d_in[16];
  const float* Wv1  = (const float*)d_in[17];
  const float* bv1  = (const float*)d_in[18];
  const float* lnvg = (const float*)d_in[19];
  const float* lnvb = (const float*)d_in[20];
  const float* Wv2  = (const float*)d_in[21];
  const float* bv2  = (const float*)d_in[22];
  const float* Wq2  = (const float*)d_in[23];
  const float* bq2  = (const float*)d_in[24];
  const float* Wk2  = (const float*)d_in[25];
  const float* bk2  = (const float*)d_in[26];

  float* ws = (float*)d_ws;
  float* e_ws  = ws;                                   // B*D*S*64
  float* wq2w  = e_ws + (size_t)Bv*Dv*Sv*64;           // B*S*D  ([b][s][k])
  float* wv_ws = wq2w + (size_t)Bv*Sv*Dv;              // B*D*S
  float* sc1   = wv_ws + (size_t)Bv*Dv*Sv;             // B*S*D
  float* out1  = sc1 + (size_t)Bv*Sv*Dv;               // B*S
  float* wqa   = out1 + (size_t)Bv*Sv;                 // B*S
  float* sc2   = wqa + (size_t)Bv*Sv;                  // B*S

  float* out = (float*)d_out;
  float* out_c1 = out + 256 + Bv*Sv;                   // contributes1 offset

  hipLaunchKernelGGL(k1_fe2, dim3(Dv*256), dim3(128), 0, stream,
    x, W1, b1, W2, b2, Wl, bl, Wq, bq, Wv1, bv1, lnvg, lnvb, Wv2, bv2,
    e_ws, wq2w, wv_ws);
  hipLaunchKernelGGL(k2_fused, dim3(Bv*Dv/2), dim3(128), 0, stream,
    e_ws, Wb1, bb1, lng, lnb, Wb2, bb2, Wk, bk, wq2w, sc1);
  hipLaunchKernelGGL(k3_att1, dim3(Bv*Sv), dim3(256), 0, stream,
    sc1, wv_ws, e_ws, Wq2, bq2, out_c1, out1, wqa);
  hipLaunchKernelGGL(k4_gemm, dim3(Bv), dim3(256), 0, stream,
    e_ws, Wk2, bk2, wqa, sc2);
  hipLaunchKernelGGL(k5_final, dim3(Bv), dim3(64), 0, stream, sc2, out1, out);
}

// Round 4
// 1010.287 us; speedup vs baseline: 2.8538x; 1.1794x over previous
//
#include <hip/hip_runtime.h>
#include <math.h>

#define Bv 256
#define Dv 38
#define Sv 64
#define SWv 10
#define EPSv 1e-5f

typedef float f4 __attribute__((ext_vector_type(4)));

__device__ __forceinline__ float leaky(float v){ return v > 0.f ? v : 0.01f*v; }
__device__ __forceinline__ float sigm(float v){ return 1.f/(1.f+expf(-v)); }

__device__ __forceinline__ float wred64(float v){
  #pragma unroll
  for (int off=32; off; off>>=1) v += __shfl_xor(v, off, 64);
  return v;
}
__device__ __forceinline__ float wmax64(float v){
  #pragma unroll
  for (int off=32; off; off>>=1) v = fmaxf(v, __shfl_xor(v, off, 64));
  return v;
}

// ---------------- K0: pre-transpose weights into ws ----------------
// wlT[d][c=8][q=16][o=68]: q=ch*4+io <-> f=ch*31+4c+io (zero-pad invalid)
// w1T[d][w=10][o=68]; wv1T[d][o=64][h=36]
__global__ __launch_bounds__(256) void k0_pack(
    const float* __restrict__ Wl, const float* __restrict__ W1,
    const float* __restrict__ Wv1,
    float* __restrict__ wlT, float* __restrict__ w1T, float* __restrict__ wv1T)
{
  int idx = blockIdx.x*256 + threadIdx.x;
  if (idx < 330752) {
    int d = idx / 8704, r = idx % 8704;
    int c = r / 1088, rr = r % 1088;
    int q = rr / 68, o = rr % 68;
    int ch = q >> 2, io = q & 3, fi = 4*c + io;
    float v = 0.f;
    if (o < 64 && fi <= 30) v = Wl[d*7936 + o*124 + ch*31 + fi];
    wlT[idx] = v;
  } else if (idx < 330752 + 25840) {
    int t = idx - 330752;
    int d = t / 680, rr = t % 680;
    int w = rr / 68, o = rr % 68;
    w1T[t] = (o < 64) ? W1[d*640 + o*10 + w] : 0.f;
  } else if (idx < 330752 + 25840 + 87552) {
    int t = idx - 330752 - 25840;
    int d = t / 2304, rr = t % 2304;
    int o = rr / 36, h = rr % 36;
    wv1T[t] = (h < 32) ? Wv1[d*2048 + h*64 + o] : 0.f;
  }
}

// ---------------- K1: FE1 + conv/pool + embed + wq + v/wv, pipelined ----------------
// One (b,d) per 128-thread block. LDS (floats, all strides 68 / f4-aligned):
//   F1T @0     [64][68]=4352   f1T -> eT
//   MT0 @4352  2x[16][68]=2176 (FE1 phase: W1T@4352(680), AT@5032(680))
//   WL0 @6528  2x[16][68]=2176
//   v-phase aliases: Wv1T@4352(2304), pts@6656(576), ptq@7232(576),
//                    mu@7808(64), rs@7872(64), wqp@8128(576)
//   consts @8704: b1,bl,Wq,W2@8896,b2@8908,bv1@8912,lnvg@8944,lnvb@8976,Wv2@9008
__global__ __launch_bounds__(128) void k1_fe3(
    const float* __restrict__ x,
    const float* __restrict__ w1T_all, const float* __restrict__ b1,
    const float* __restrict__ W2, const float* __restrict__ b2,
    const float* __restrict__ wlT_all, const float* __restrict__ bl,
    const float* __restrict__ Wq, const float* __restrict__ bq,
    const float* __restrict__ wv1T_all, const float* __restrict__ bv1,
    const float* __restrict__ lnvg, const float* __restrict__ lnvb,
    const float* __restrict__ Wv2, const float* __restrict__ bv2,
    float* __restrict__ e_ws, float* __restrict__ wq2_ws, float* __restrict__ wv_ws)
{
  __shared__ float sm[9040];
  const int d = blockIdx.x >> 8;
  const int b = blockIdx.x & 255;
  const int tid = threadIdx.x;
  const int tx = tid & 15, ty = tid >> 4;   // ty 0..7
  const int bd = b*Dv + d;

#define PJ(j) ((j) < 4 ? 4*ty + (j) : 32 + 4*ty + ((j)-4))
#define MT0o 4352
#define WL0o 6528

  // ---- preload Wl chunk 0 into regs (earliest) ----
  const f4* wlsrc = (const f4*)(wlT_all + (size_t)d*8704);
  f4 wr0 = wlsrc[tid];
  f4 wr1 = wlsrc[tid+128];
  f4 wr2 = {0.f,0.f,0.f,0.f};
  if (tid < 16) wr2 = wlsrc[tid+256];

  // ---- stage consts ----
  if (tid < 64) {
    sm[8704+tid] = b1[d*64+tid];
    sm[8768+tid] = bl[d*64+tid];
    sm[8832+tid] = Wq[tid];
  } else {
    int t = tid-64;
    if (t < 32) {
      sm[8912+t]=bv1[d*32+t]; sm[8944+t]=lnvg[d*32+t];
      sm[8976+t]=lnvb[d*32+t]; sm[9008+t]=Wv2[d*32+t];
    } else if (t < 44) sm[8896+(t-32)] = W2[d*12+(t-32)];
    else if (t < 48) sm[8908+(t-44)] = b2[d*4+(t-44)];
  }
  // ---- stage W1T (170 f4) @4352, AT (transpose) @5032 ----
  {
    const f4* s4 = (const f4*)(w1T_all + (size_t)d*680);
    ((f4*)&sm[4352])[tid] = s4[tid];
    if (tid < 42) ((f4*)&sm[4352])[tid+128] = s4[tid+128];
  }
  {
    const float* xg = x + (size_t)bd*640;
    for (int t = tid; t < 640; t += 128) {
      int s = t/10, w = t%10;
      sm[5032 + w*68 + s] = xg[t];
    }
  }
  __syncthreads();

  // ---- FE1 GEMM: fe[s=4tx+i][o=PJ(j)], K=10 ----
  float fe[4][8];
  #pragma unroll
  for (int i=0;i<4;++i)
    #pragma unroll
    for (int j=0;j<8;++j) fe[i][j]=0.f;
  #pragma unroll
  for (int w = 0; w < 10; ++w) {
    f4 a   = *(const f4*)&sm[5032 + w*68 + 4*tx];
    f4 blo = *(const f4*)&sm[4352 + w*68 + 4*ty];
    f4 bhi = *(const f4*)&sm[4352 + w*68 + 32 + 4*ty];
    float bv8[8] = {blo[0],blo[1],blo[2],blo[3],bhi[0],bhi[1],bhi[2],bhi[3]};
    #pragma unroll
    for (int i=0;i<4;++i)
      #pragma unroll
      for (int j=0;j<8;++j) fe[i][j] += a[i]*bv8[j];
  }
  // write f1T as f4 along s (conflict-light); Wl[0]; preload chunk1
  #pragma unroll
  for (int j=0;j<8;++j) {
    int o = PJ(j);
    float bb = sm[8704+o];
    f4 v = {leaky(fe[0][j]+bb), leaky(fe[1][j]+bb), leaky(fe[2][j]+bb), leaky(fe[3][j]+bb)};
    *(f4*)&sm[o*68 + 4*tx] = v;
  }
  {
    f4* dst = (f4*)&sm[WL0o];
    dst[tid]=wr0; dst[tid+128]=wr1; if (tid<16) dst[tid+256]=wr2;
    const f4* s = wlsrc + 272;
    wr0 = s[tid]; wr1 = s[tid+128]; if (tid<16) wr2 = s[tid+256];
  }
  __syncthreads();

  // ---- conv(0) -> mT0; Wl[1]; preload chunk2 ----
  {
    int s = tid & 63, ioh = tid >> 6;
    float* mdst = &sm[MT0o];
    #pragma unroll
    for (int io2=0; io2<2; ++io2) {
      int io = 2*ioh + io2;
      int fi = io;                       // c=0
      int t0 = 2*fi - 1;
      float v0 = (t0<0)?0.f:sm[t0*68+s];
      float v1 = sm[(t0+1)*68+s];
      float v2 = sm[(t0+2)*68+s];
      float v3 = sm[(t0+3)*68+s];
      float v4 = sm[(t0+4)*68+s];
      #pragma unroll
      for (int ch=0; ch<4; ++ch) {
        float w0=sm[8896+ch*3], w1=sm[8896+ch*3+1], w2=sm[8896+ch*3+2];
        float bb=sm[8908+ch];
        float ca = bb + v0*w0 + v1*w1 + v2*w2;
        float cb = bb + v1*w0 + v2*w1 + v3*w2;
        float cc2= bb + v2*w0 + v3*w1 + v4*w2;
        mdst[(ch*4+io)*68+s] = fmaxf(fmaxf(leaky(ca),leaky(cb)),leaky(cc2));
      }
    }
    f4* dst = (f4*)&sm[WL0o + 1088];
    dst[tid]=wr0; dst[tid+128]=wr1; if (tid<16) dst[tid+256]=wr2;
    const f4* s2 = wlsrc + 2*272;
    wr0 = s2[tid]; wr1 = s2[tid+128]; if (tid<16) wr2 = s2[tid+256];
  }
  __syncthreads();

  // ---- embed pipeline: 8 chunks K=16, double-buffered mT/WlT ----
  float ea[4][8];
  #pragma unroll
  for (int i=0;i<4;++i)
    #pragma unroll
    for (int j=0;j<8;++j) ea[i][j]=0.f;

  for (int c = 0; c < 8; ++c) {
    if (c >= 1 && c <= 6) {
      f4* dst = (f4*)&sm[WL0o + ((c+1)&1)*1088];
      dst[tid]=wr0; dst[tid+128]=wr1; if (tid<16) dst[tid+256]=wr2;
      if (c <= 5) {
        const f4* s = wlsrc + (c+2)*272;
        wr0 = s[tid]; wr1 = s[tid+128]; if (tid<16) wr2 = s[tid+256];
      }
    }
    {
      const float* ma = &sm[MT0o + (c&1)*1088];
      const float* wb = &sm[WL0o + (c&1)*1088];
      #pragma unroll
      for (int q=0;q<16;++q){
        f4 a   = *(const f4*)&ma[q*68+4*tx];
        f4 blo = *(const f4*)&wb[q*68+4*ty];
        f4 bhi = *(const f4*)&wb[q*68+32+4*ty];
        float bv8[8] = {blo[0],blo[1],blo[2],blo[3],bhi[0],bhi[1],bhi[2],bhi[3]};
        #pragma unroll
        for (int i=0;i<4;++i)
          #pragma unroll
          for (int j=0;j<8;++j) ea[i][j] += a[i]*bv8[j];
      }
    }
    if (c < 7) {
      int cc = c+1;
      int s = tid & 63, ioh = tid >> 6;
      float* mdst = &sm[MT0o + (cc&1)*1088];
      #pragma unroll
      for (int io2=0; io2<2; ++io2) {
        int io = 2*ioh + io2;
        int fi = 4*cc + io;
        if (fi <= 30) {
          int t0 = 2*fi - 1;
          float v0 = sm[t0*68+s];
          float v1 = sm[(t0+1)*68+s];
          float v2 = sm[(t0+2)*68+s];
          float v3 = sm[(t0+3)*68+s];
          float v4 = sm[(t0+4)*68+s];
          #pragma unroll
          for (int ch=0; ch<4; ++ch) {
            float w0=sm[8896+ch*3], w1=sm[8896+ch*3+1], w2=sm[8896+ch*3+2];
            float bb=sm[8908+ch];
            float ca = bb + v0*w0 + v1*w1 + v2*w2;
            float cb = bb + v1*w0 + v2*w1 + v3*w2;
            float cc2= bb + v2*w0 + v3*w1 + v4*w2;
            mdst[(ch*4+io)*68+s] = fmaxf(fmaxf(leaky(ca),leaky(cb)),leaky(cc2));
          }
        } else {
          #pragma unroll
          for (int ch=0; ch<4; ++ch) mdst[(ch*4+io)*68+s] = 0.f;
        }
      }
    }
    __syncthreads();
  }

  // ---- epilogue: e -> e_ws/eT/wq partials; preload Wv1T ----
  float ev[4][8];
  #pragma unroll
  for (int i=0;i<4;++i)
    #pragma unroll
    for (int j=0;j<8;++j) ev[i][j] = leaky(ea[i][j] + sm[8768 + PJ(j)]);

  {
    float* erow = e_ws + (size_t)bd * 4096;
    #pragma unroll
    for (int i=0;i<4;++i) {
      f4 lo = {ev[i][0],ev[i][1],ev[i][2],ev[i][3]};
      f4 hi = {ev[i][4],ev[i][5],ev[i][6],ev[i][7]};
      *(f4*)&erow[(4*tx+i)*64 + 4*ty] = lo;
      *(f4*)&erow[(4*tx+i)*64 + 32 + 4*ty] = hi;
    }
  }
  #pragma unroll
  for (int j=0;j<8;++j) {
    int o = PJ(j);
    f4 v = {ev[0][j],ev[1][j],ev[2][j],ev[3][j]};
    *(f4*)&sm[o*68 + 4*tx] = v;      // eT over f1T
  }
  #pragma unroll
  for (int i=0;i<4;++i) {
    float p = 0.f;
    #pragma unroll
    for (int j=0;j<8;++j) p += ev[i][j]*sm[8832 + PJ(j)];
    sm[8128 + (4*tx+i)*9 + ty] = p;  // wq partials
  }
  // preload Wv1T (576 f4)
  f4 w0r,w1r,w2r,w3r,w4r;
  {
    const f4* s4 = (const f4*)(wv1T_all + (size_t)d*2304);
    w0r=s4[tid]; w1r=s4[tid+128]; w2r=s4[tid+256]; w3r=s4[tid+384];
    if (tid<64) w4r=s4[tid+512];
  }
  __syncthreads();

  // ---- write Wv1T; wq reduce ----
  {
    f4* dst = (f4*)&sm[4352];
    dst[tid]=w0r; dst[tid+128]=w1r; dst[tid+256]=w2r; dst[tid+384]=w3r;
    if (tid<64) dst[tid+512]=w4r;
  }
  if (tid < 64) {
    float p = 0.f;
    #pragma unroll
    for (int y=0;y<8;++y) p += sm[8128 + tid*9 + y];
    wq2_ws[((size_t)b*64 + tid)*Dv + d] = sigm(p + bq[0]);
  }
  __syncthreads();

  // ---- v-GEMM: va[s][h], K=64 ----
  float va[4][4];
  #pragma unroll
  for (int i=0;i<4;++i)
    #pragma unroll
    for (int j=0;j<4;++j) va[i][j]=0.f;
  #pragma unroll 8
  for (int o = 0; o < 64; ++o) {
    f4 a  = *(const f4*)&sm[o*68 + 4*tx];
    f4 bb = *(const f4*)&sm[4352 + o*36 + 4*ty];
    #pragma unroll
    for (int i=0;i<4;++i)
      #pragma unroll
      for (int j=0;j<4;++j) va[i][j] += a[i]*bb[j];
  }
  #pragma unroll
  for (int i=0;i<4;++i)
    #pragma unroll
    for (int j=0;j<4;++j) va[i][j] += sm[8912 + 4*ty + j];

  // LN partials
  #pragma unroll
  for (int i=0;i<4;++i) {
    float ps=0.f, pq=0.f;
    #pragma unroll
    for (int j=0;j<4;++j) { ps += va[i][j]; pq += va[i][j]*va[i][j]; }
    sm[6656 + (4*tx+i)*9 + ty] = ps;
    sm[7232 + (4*tx+i)*9 + ty] = pq;
  }
  __syncthreads();
  if (tid < 64) {
    float s_=0.f, q_=0.f;
    #pragma unroll
    for (int y=0;y<8;++y) { s_ += sm[6656 + tid*9 + y]; q_ += sm[7232 + tid*9 + y]; }
    float mu = s_*(1.f/32.f);
    float vr = q_*(1.f/32.f) - mu*mu;
    sm[7808 + tid] = mu;
    sm[7872 + tid] = rsqrtf(vr + EPSv);
  }
  __syncthreads();
  #pragma unroll
  for (int i=0;i<4;++i) {
    float mu = sm[7808 + 4*tx + i];
    float rs = sm[7872 + 4*tx + i];
    float p = 0.f;
    #pragma unroll
    for (int j=0;j<4;++j) {
      int h = 4*ty + j;
      float vh = leaky(sm[8944+h]*(va[i][j]-mu)*rs + sm[8976+h]);
      p += vh*sm[9008+h];
    }
    sm[6656 + (4*tx+i)*9 + ty] = p;
  }
  __syncthreads();
  if (tid < 64) {
    float p = 0.f;
    #pragma unroll
    for (int y=0;y<8;++y) p += sm[6656 + tid*9 + y];
    wv_ws[(size_t)bd*64 + tid] = fmaxf(p + bv2[d], 0.f);
  }
#undef PJ
#undef MT0o
#undef WL0o
}

// ---------------- K2: fused Wb1+LN+Wb2+cumsum+Wk/wq -> score1 ----------------
__global__ __launch_bounds__(128) void k2_fused(
    const float* __restrict__ e_ws,
    const float* __restrict__ Wb1, const float* __restrict__ bb1,
    const float* __restrict__ lng, const float* __restrict__ lnb,
    const float* __restrict__ Wb2, const float* __restrict__ bb2,
    const float* __restrict__ Wk, const float* __restrict__ bk,
    const float* __restrict__ wq2_ws, float* __restrict__ score1)
{
  __shared__ float smem[16384];           // 64 KiB, phase-aliased
  float* bufA = smem;                     // 8192 f  [64][128]: EsT -> HnT -> AcmlT
  float* bufB = smem + 8192;              // 4096 f  [64][64]:  W1T -> pts/ptq/stats -> WkT[64][40]
  float* bufC = smem + 12288;             // 4096 f  [64][64]:  W2T -> pt2[128][9]

  const int tid = threadIdx.x;
  const int tx = tid & 15;
  const int ty = tid >> 4;                // 0..7
  const int bd0 = blockIdx.x * 2;
  const int bd1 = bd0 + 1;

#define RI(i) ((i) < 4 ? 4*tx + (i) : 64 + 4*tx + ((i)-4))
#define PJ(j) ((j) < 4 ? 4*ty + (j) : 32 + 4*ty + ((j)-4))

  // ---- stage EsT (bufA), W1T (bufB), W2T (bufC), transposed ----
  {
    const int r0 = tid & 15, c0 = tid >> 4;      // c0 0..7
    const f4* Esrc  = (const f4*)(e_ws + (size_t)bd0 * 4096);
    #pragma unroll
    for (int p = 0; p < 2; ++p) {
      int oc = c0 + 8*p;
      #pragma unroll
      for (int q = 0; q < 8; ++q) {
        int r = r0 + 16*q;
        f4 v = Esrc[r*16 + oc];
        #pragma unroll
        for (int k = 0; k < 4; ++k) bufA[(4*oc+k)*128 + r] = v[k];
      }
    }
    const f4* W1src = (const f4*)Wb1;
    const f4* W2src = (const f4*)Wb2;
    #pragma unroll
    for (int p = 0; p < 2; ++p) {
      int oc = c0 + 8*p;
      #pragma unroll
      for (int q = 0; q < 4; ++q) {
        int rr = r0 + 16*q;
        f4 v1 = W1src[rr*16 + oc];
        f4 v2 = W2src[rr*16 + oc];
        #pragma unroll
        for (int k = 0; k < 4; ++k) {
          bufB[(4*oc+k)*64 + rr] = v1[k];
          bufC[(4*oc+k)*64 + rr] = v2[k];
        }
      }
    }
  }
  __syncthreads();

  // per-thread column constants
  float bb1v[8], lngv[8], lnbv[8], bb2v[8];
  #pragma unroll
  for (int j=0;j<8;++j) {
    int p = PJ(j);
    bb1v[j]=bb1[p]; lngv[j]=lng[p]; lnbv[j]=lnb[p]; bb2v[j]=bb2[p];
  }

  // ---- GEMM1: h[r][p] = sum_o E[r][o]*Wb1[p][o] ----
  float h[8][8];
  #pragma unroll
  for (int i=0;i<8;++i)
    #pragma unroll
    for (int j=0;j<8;++j) h[i][j]=0.f;
  for (int o = 0; o < 64; ++o) {
    f4 al = *(const f4*)(bufA + o*128 + 4*tx);
    f4 ah = *(const f4*)(bufA + o*128 + 64 + 4*tx);
    f4 bl = *(const f4*)(bufB + o*64 + 4*ty);
    f4 bh = *(const f4*)(bufB + o*64 + 32 + 4*ty);
    float av[8] = {al[0],al[1],al[2],al[3],ah[0],ah[1],ah[2],ah[3]};
    float bv[8] = {bl[0],bl[1],bl[2],bl[3],bh[0],bh[1],bh[2],bh[3]};
    #pragma unroll
    for (int i=0;i<8;++i)
      #pragma unroll
      for (int j=0;j<8;++j) h[i][j] += av[i]*bv[j];
  }
  #pragma unroll
  for (int i=0;i<8;++i)
    #pragma unroll
    for (int j=0;j<8;++j) h[i][j] += bb1v[j];

  // ---- LN stats: partials in bufB (W1T dead) ----
  __syncthreads();
  float* pts = bufB;              // [128][9]
  float* ptq = bufB + 1152;       // [128][9]
  float* stmu = bufB + 2304;      // [128]
  float* strs = bufB + 2432;      // [128]
  #pragma unroll
  for (int i=0;i<8;++i) {
    float ps=0.f, pq=0.f;
    #pragma unroll
    for (int j=0;j<8;++j) { ps += h[i][j]; pq += h[i][j]*h[i][j]; }
    pts[RI(i)*9 + ty] = ps;
    ptq[RI(i)*9 + ty] = pq;
  }
  __syncthreads();
  {
    float s=0.f, q=0.f;
    #pragma unroll
    for (int y=0;y<8;++y) { s += pts[tid*9+y]; q += ptq[tid*9+y]; }
    float mu = s*(1.f/64.f);
    float va = q*(1.f/64.f) - mu*mu;
    stmu[tid] = mu;
    strs[tid] = rsqrtf(va + EPSv);
  }
  __syncthreads();

  // ---- normalize + leaky, write HnT into bufA (E dead) ----
  {
    float muv[8], rsv[8];
    #pragma unroll
    for (int i=0;i<8;++i) { muv[i]=stmu[RI(i)]; rsv[i]=strs[RI(i)]; }
    #pragma unroll
    for (int i=0;i<8;++i)
      #pragma unroll
      for (int j=0;j<8;++j) {
        float hn = leaky(lngv[j]*(h[i][j]-muv[i])*rsv[i] + lnbv[j]);
        bufA[PJ(j)*128 + RI(i)] = hn;
      }
  }
  __syncthreads();

  // ---- GEMM2: g[r][q] = sum_p Hn[r][p]*Wb2[q][p] ----
  float gacc[8][8];
  #pragma unroll
  for (int i=0;i<8;++i)
    #pragma unroll
    for (int j=0;j<8;++j) gacc[i][j]=0.f;
  for (int p = 0; p < 64; ++p) {
    f4 al = *(const f4*)(bufA + p*128 + 4*tx);
    f4 ah = *(const f4*)(bufA + p*128 + 64 + 4*tx);
    f4 bl = *(const f4*)(bufC + p*64 + 4*ty);
    f4 bh = *(const f4*)(bufC + p*64 + 32 + 4*ty);
    float av[8] = {al[0],al[1],al[2],al[3],ah[0],ah[1],ah[2],ah[3]};
    float bv[8] = {bl[0],bl[1],bl[2],bl[3],bh[0],bh[1],bh[2],bh[3]};
    #pragma unroll
    for (int i=0;i<8;++i)
      #pragma unroll
      for (int j=0;j<8;++j) gacc[i][j] += av[i]*bv[j];
  }
  #pragma unroll
  for (int i=0;i<8;++i)
    #pragma unroll
    for (int j=0;j<8;++j) gacc[i][j] = leaky(gacc[i][j] + bb2v[j]);

  // ---- cumsum over s (per 64-row group) via 16-lane segment scan ----
  #pragma unroll
  for (int j=0;j<8;++j) {
    {
      float c0=gacc[0][j], c1=c0+gacc[1][j], c2=c1+gacc[2][j], c3=c2+gacc[3][j];
      float incl = c3;
      #pragma unroll
      for (int dd=1; dd<16; dd<<=1) {
        float t = __shfl_up(incl, dd, 16);
        if ((tid & 15) >= dd) incl += t;
      }
      float ex = incl - c3;
      gacc[0][j]=ex+c0; gacc[1][j]=ex+c1; gacc[2][j]=ex+c2; gacc[3][j]=ex+c3;
    }
    {
      float c0=gacc[4][j], c1=c0+gacc[5][j], c2=c1+gacc[6][j], c3=c2+gacc[7][j];
      float incl = c3;
      #pragma unroll
      for (int dd=1; dd<16; dd<<=1) {
        float t = __shfl_up(incl, dd, 16);
        if ((tid & 15) >= dd) incl += t;
      }
      float ex = incl - c3;
      gacc[4][j]=ex+c0; gacc[5][j]=ex+c1; gacc[6][j]=ex+c2; gacc[7][j]=ex+c3;
    }
  }
  __syncthreads();

  // ---- write AcmlT into bufA; stage WkT [64][40] into bufB ----
  #pragma unroll
  for (int i=0;i<8;++i)
    #pragma unroll
    for (int j=0;j<8;++j) bufA[PJ(j)*128 + RI(i)] = gacc[i][j];
  for (int i2 = tid; i2 < 2560; i2 += 128) {
    int q = i2/40, k = i2%40;
    bufB[i2] = (k < Dv) ? Wk[k*64 + q] : 0.f;
  }
  __syncthreads();

  // ---- GEMM3: u[r][k] = sum_q acml[r][q]*Wk[k][q] (k<38) ----
  float u[8][4], u2[8][4];
  #pragma unroll
  for (int i=0;i<8;++i)
    #pragma unroll
    for (int j=0;j<4;++j) { u[i][j]=0.f; u2[i][j]=0.f; }
  for (int q = 0; q < 64; ++q) {
    f4 al = *(const f4*)(bufA + q*128 + 4*tx);
    f4 ah = *(const f4*)(bufA + q*128 + 64 + 4*tx);
    f4 b1v = *(const f4*)(bufB + q*40 + 4*ty);
    float av[8] = {al[0],al[1],al[2],al[3],ah[0],ah[1],ah[2],ah[3]};
    #pragma unroll
    for (int i=0;i<8;++i)
      #pragma unroll
      for (int j=0;j<4;++j) u[i][j] += av[i]*b1v[j];
    if (ty < 2) {
      f4 b2v = *(const f4*)(bufB + q*40 + 32 + 4*ty);
      #pragma unroll
      for (int i=0;i<8;++i)
        #pragma unroll
        for (int j=0;j<4;++j) u2[i][j] += av[i]*b2v[j];
    }
  }

  // ---- epilogue: sigm(u+bk)*wq, reduce over k -> score1 ----
  const int b0g = bd0/Dv, d0g = bd0%Dv, b1g = bd1/Dv, d1g = bd1%Dv;
  float* pt2 = bufC;   // [128][9]
  #pragma unroll
  for (int i=0;i<8;++i) {
    int s = 4*tx + (i & 3);
    int bb_ = (i<4) ? b0g : b1g;
    const float* wqrow = wq2_ws + ((size_t)bb_*Sv + s)*Dv;
    float p = 0.f;
    #pragma unroll
    for (int j=0;j<4;++j) {
      int k = 4*ty + j;
      p += sigm(u[i][j] + bk[k]) * wqrow[k];
    }
    if (ty < 2) {
      #pragma unroll
      for (int j=0;j<4;++j) {
        int k = 32 + 4*ty + j;
        if (k < Dv) p += sigm(u2[i][j] + bk[k]) * wqrow[k];
      }
    }
    pt2[RI(i)*9 + ty] = p;
  }
  __syncthreads();
  {
    int rr = tid;                 // 0..127
    float tot = 0.f;
    #pragma unroll
    for (int y=0;y<8;++y) tot += pt2[rr*9+y];
    int grp = rr >> 6, s = rr & 63;
    int bb_ = grp ? b1g : b0g;
    int dd_ = grp ? d1g : d0g;
    score1[((size_t)bb_*Sv + s)*Dv + dd_] = tot;
  }
#undef RI
#undef PJ
}

// ---------------- K3: att1 softmax + contributes1/output1 + wq_a ----------------
__global__ __launch_bounds__(256) void k3_att1(
    const float* __restrict__ score1, const float* __restrict__ wv_ws,
    const float* __restrict__ e_ws, const float* __restrict__ Wq2, const float* __restrict__ bq2,
    float* __restrict__ out_c1, float* __restrict__ output1, float* __restrict__ wq_a)
{
  const int blk = blockIdx.x;
  const int b = blk / Sv, s = blk % Sv;
  const int tid = threadIdx.x;
  const int wid = tid>>6, lane = tid&63;
  __shared__ float red[4];

  if (wid==0) {
    const float invsq = 0.16222142113076254f; // 1/sqrt(38)
    float sc = (lane<Dv) ? score1[(b*Sv+s)*Dv+lane]*invsq : -1e30f;
    float mx = wmax64(sc);
    float ex = (lane<Dv) ? expf(sc-mx) : 0.f;
    float den = wred64(ex);
    float att = ex/den;
    float c1 = 0.f;
    if (lane<Dv) {
      c1 = wv_ws[(b*Dv+lane)*Sv+s]*att;
      out_c1[(b*Sv+s)*Dv+lane] = c1;
    }
    float tot = wred64(c1);
    if (lane==0) output1[b*Sv+s] = tot;
  }
  // wq_a[b,s] = sigmoid(ef[b,s]·Wq2 + bq2)
  float p = 0.f;
  for (int idx=tid; idx<Dv*64; idx+=256) {
    int d = idx>>6, o = idx&63;
    p += e_ws[((size_t)(b*Dv+d)*Sv+s)*64+o]*Wq2[idx];
  }
  p = wred64(p);
  if (lane==0) red[wid]=p;
  __syncthreads();
  if (tid==0) wq_a[b*Sv+s] = sigm(red[0]+red[1]+red[2]+red[3]+bq2[0]);
}

// ---------------- K4: per-b 64x64x2432 GEMM + fused score2 ----------------
__global__ __launch_bounds__(256) void k4_gemm(
    const float* __restrict__ e_ws, const float* __restrict__ Wk2, const float* __restrict__ bk2,
    const float* __restrict__ wq_a, float* __restrict__ score2)
{
  const int b = blockIdx.x;
  const int tid = threadIdx.x;
  const int tx = tid & 15, ty = tid >> 4;       // tile coords
  __shared__ float AsT[64*68];
  __shared__ float BsT[64*68];
  __shared__ float pt[64*17];

  float acc[4][4];
  #pragma unroll
  for (int i=0;i<4;++i)
    #pragma unroll
    for (int j=0;j<4;++j) acc[i][j]=0.f;

  const int r0 = tid & 15, oc0 = tid >> 4;      // staging map
  const f4* Bsrc = (const f4*)Wk2;              // row stride 608 f4

  for (int d = 0; d < 38; ++d) {
    const f4* Asrc = (const f4*)(e_ws + ((size_t)(b*Dv+d))*4096);
    #pragma unroll
    for (int q = 0; q < 4; ++q) {
      int r = r0 + 16*q;
      f4 av = Asrc[r*16 + oc0];
      f4 bv = Bsrc[(size_t)r*608 + d*16 + oc0];
      #pragma unroll
      for (int k = 0; k < 4; ++k) {
        AsT[(4*oc0+k)*68 + r] = av[k];
        BsT[(4*oc0+k)*68 + r] = bv[k];
      }
    }
    __syncthreads();
    #pragma unroll 4
    for (int o = 0; o < 64; ++o) {
      f4 a  = *(const f4*)&AsT[o*68 + 4*tx];
      f4 bb = *(const f4*)&BsT[o*68 + 4*ty];
      #pragma unroll
      for (int i=0;i<4;++i)
        #pragma unroll
        for (int j=0;j<4;++j) acc[i][j] += a[i]*bb[j];
    }
    __syncthreads();
  }

  // epilogue: score2[b,t] = sum_s sigm(C[t,s]+bk2[s])*wq_a[b,s]
  #pragma unroll
  for (int i=0;i<4;++i) {
    float p = 0.f;
    #pragma unroll
    for (int j=0;j<4;++j) {
      int s = 4*ty + j;
      p += sigm(acc[i][j] + bk2[s]) * wq_a[b*Sv + s];
    }
    pt[(4*tx+i)*17 + ty] = p;
  }
  __syncthreads();
  if (tid < 64) {
    float tot = 0.f;
    #pragma unroll
    for (int y=0;y<16;++y) tot += pt[tid*17+y];
    score2[b*Sv + tid] = tot;
  }
}

// ---------------- K5: att2 softmax + contributes2/output2 ----------------
__global__ __launch_bounds__(64) void k5_final(
    const float* __restrict__ score2, const float* __restrict__ output1,
    float* __restrict__ out)
{
  const int b = blockIdx.x;
  const int lane = threadIdx.x;
  const float inv = 0.039528470752104741f; // 1/sqrt(640)
  float v = score2[b*Sv+lane]*inv;
  float mx = wmax64(v);
  float ex = expf(v-mx);
  float den = wred64(ex);
  float att = ex/den;
  float c2 = output1[b*Sv+lane]*att;
  out[256 + b*Sv + lane] = c2;     // contributes2
  float tot = wred64(c2);
  if (lane==0) out[b] = tot;       // output2
}

extern "C" void kernel_launch(void* const* d_in, const int* in_sizes, int n_in,
                              void* d_out, int out_size, void* d_ws, size_t ws_size,
                              hipStream_t stream)
{
  const float* x    = (const float*)d_in[0];
  const float* W1   = (const float*)d_in[1];
  const float* b1   = (const float*)d_in[2];
  const float* W2   = (const float*)d_in[3];
  const float* b2   = (const float*)d_in[4];
  const float* Wl   = (const float*)d_in[5];
  const float* bl   = (const float*)d_in[6];
  const float* Wb1  = (const float*)d_in[7];
  const float* bb1  = (const float*)d_in[8];
  const float* lng  = (const float*)d_in[9];
  const float* lnb  = (const float*)d_in[10];
  const float* Wb2  = (const float*)d_in[11];
  const float* bb2  = (const float*)d_in[12];
  const float* Wq   = (const float*)d_in[13];
  const float* bq   = (const float*)d_in[14];
  const float* Wk   = (const float*)d_in[15];
  const float* bk   = (const float*)d_in[16];
  const float* Wv1  = (const float*)d_in[17];
  const float* bv1  = (const float*)d_in[18];
  const float* lnvg = (const float*)d_in[19];
  const float* lnvb = (const float*)d_in[20];
  const float* Wv2  = (const float*)d_in[21];
  const float* bv2  = (const float*)d_in[22];
  const float* Wq2  = (const float*)d_in[23];
  const float* bq2  = (const float*)d_in[24];
  const float* Wk2  = (const float*)d_in[25];
  const float* bk2  = (const float*)d_in[26];

  float* ws = (float*)d_ws;
  float* e_ws  = ws;                                   // B*D*S*64
  float* wq2w  = e_ws + (size_t)Bv*Dv*Sv*64;           // B*S*D  ([b][s][k])
  float* wv_ws = wq2w + (size_t)Bv*Sv*Dv;              // B*D*S
  float* sc1   = wv_ws + (size_t)Bv*Dv*Sv;             // B*S*D
  float* out1  = sc1 + (size_t)Bv*Sv*Dv;               // B*S
  float* wqa   = out1 + (size_t)Bv*Sv;                 // B*S
  float* sc2   = wqa + (size_t)Bv*Sv;                  // B*S
  float* wlT   = sc2 + (size_t)Bv*Sv;                  // 38*8*16*68 = 330752
  float* w1T   = wlT + 330752;                         // 38*10*68 = 25840
  float* wv1T  = w1T + 25840;                          // 38*64*36 = 87552

  float* out = (float*)d_out;
  float* out_c1 = out + 256 + Bv*Sv;                   // contributes1 offset

  hipLaunchKernelGGL(k0_pack, dim3(1736), dim3(256), 0, stream,
    Wl, W1, Wv1, wlT, w1T, wv1T);
  hipLaunchKernelGGL(k1_fe3, dim3(Dv*256), dim3(128), 0, stream,
    x, w1T, b1, W2, b2, wlT, bl, Wq, bq, wv1T, bv1, lnvg, lnvb, Wv2, bv2,
    e_ws, wq2w, wv_ws);
  hipLaunchKernelGGL(k2_fused, dim3(Bv*Dv/2), dim3(128), 0, stream,
    e_ws, Wb1, bb1, lng, lnb, Wb2, bb2, Wk, bk, wq2w, sc1);
  hipLaunchKernelGGL(k3_att1, dim3(Bv*Sv), dim3(256), 0, stream,
    sc1, wv_ws, e_ws, Wq2, bq2, out_c1, out1, wqa);
  hipLaunchKernelGGL(k4_gemm, dim3(Bv), dim3(256), 0, stream,
    e_ws, Wk2, bk2, wqa, sc2);
  hipLaunchKernelGGL(k5_final, dim3(Bv), dim3(64), 0, stream, sc2, out1, out);
}

// Round 5
// 825.098 us; speedup vs baseline: 3.4943x; 1.2244x over previous
//
#include <hip/hip_runtime.h>
#include <math.h>

#define Bv 256
#define Dv 38
#define Sv 64
#define SWv 10
#define EPSv 1e-5f

typedef float f4 __attribute__((ext_vector_type(4)));

__device__ __forceinline__ float leaky(float v){ return v > 0.f ? v : 0.01f*v; }
__device__ __forceinline__ float sigm(float v){ return 1.f/(1.f+expf(-v)); }

__device__ __forceinline__ float wred64(float v){
  #pragma unroll
  for (int off=32; off; off>>=1) v += __shfl_xor(v, off, 64);
  return v;
}
__device__ __forceinline__ float wmax64(float v){
  #pragma unroll
  for (int off=32; off; off>>=1) v = fmaxf(v, __shfl_xor(v, off, 64));
  return v;
}

// ---------------- K0: pre-transpose weights into ws ----------------
// wlT[d][c=8][q=16][o=68]: q=ch*4+io <-> f=ch*31+4c+io (zero-pad invalid)
// w1T[d][w=10][o=68]; wv1T[d][o=64][h=36]
__global__ __launch_bounds__(256) void k0_pack(
    const float* __restrict__ Wl, const float* __restrict__ W1,
    const float* __restrict__ Wv1,
    float* __restrict__ wlT, float* __restrict__ w1T, float* __restrict__ wv1T)
{
  int idx = blockIdx.x*256 + threadIdx.x;
  if (idx < 330752) {
    int d = idx / 8704, r = idx % 8704;
    int c = r / 1088, rr = r % 1088;
    int q = rr / 68, o = rr % 68;
    int ch = q >> 2, io = q & 3, fi = 4*c + io;
    float v = 0.f;
    if (o < 64 && fi <= 30) v = Wl[d*7936 + o*124 + ch*31 + fi];
    wlT[idx] = v;
  } else if (idx < 330752 + 25840) {
    int t = idx - 330752;
    int d = t / 680, rr = t % 680;
    int w = rr / 68, o = rr % 68;
    w1T[t] = (o < 64) ? W1[d*640 + o*10 + w] : 0.f;
  } else if (idx < 330752 + 25840 + 87552) {
    int t = idx - 330752 - 25840;
    int d = t / 2304, rr = t % 2304;
    int o = rr / 36, h = rr % 36;
    wv1T[t] = (h < 32) ? Wv1[d*2048 + h*64 + o] : 0.f;
  }
}

// ---------------- K1: 2 batches/block, 256 threads, 4 waves ----------------
// LDS map (floats):
//   F1T[z]  @ z*4352        [64 o][68 s]   f1T -> eT
//   WL      @ 8704          [16 q][68 o]   (single buffer, reg-prefetch)
//   MT[z]   @ 9792+z*1088   [16 q][68 s]
//   FE1 aliases: W1T @9792 (680), AT[z] @10472+z*680
//   v-phase aliases: Wv1T @8704 (2304), vps @11008, vpq @11264,
//                    wqp/wvp @11520, mu @11776, rs @11904
//   consts @12032: b1, bl@12096, Wq@12160, W2@12224, b2@12236,
//                  bv1@12240, lnvg@12272, lnvb@12304, Wv2@12336
__global__ __launch_bounds__(256, 3) void k1_fe4(
    const float* __restrict__ x,
    const float* __restrict__ w1T_all, const float* __restrict__ b1,
    const float* __restrict__ W2, const float* __restrict__ b2,
    const float* __restrict__ wlT_all, const float* __restrict__ bl,
    const float* __restrict__ Wq, const float* __restrict__ bq,
    const float* __restrict__ wv1T_all, const float* __restrict__ bv1,
    const float* __restrict__ lnvg, const float* __restrict__ lnvb,
    const float* __restrict__ Wv2, const float* __restrict__ bv2,
    float* __restrict__ e_ws, float* __restrict__ wq2_ws, float* __restrict__ wv_ws)
{
  __shared__ float sm[12368];
  const int d  = blockIdx.x >> 7;
  const int b0 = (blockIdx.x & 127) * 2;
  const int tid = threadIdx.x;
  const int z = tid >> 7;                 // batch half
  const int t = tid & 127;
  const int tx = t & 15, ty = t >> 4;     // ty 0..7
  const int wz = ty >> 2;                 // wave within half
  const int bd = (b0 + z)*Dv + d;
  const float bq0 = bq[0];

#define PJ(j) ((j) < 4 ? 4*ty + (j) : 32 + 4*ty + ((j)-4))

  // ---- stage consts ----
  if (tid < 64) {
    sm[12032+tid] = b1[d*64+tid];
    sm[12096+tid] = bl[d*64+tid];
    sm[12160+tid] = Wq[tid];
  } else if (tid < 96) {
    int u = tid-64;
    sm[12240+u]=bv1[d*32+u]; sm[12272+u]=lnvg[d*32+u];
    sm[12304+u]=lnvb[d*32+u]; sm[12336+u]=Wv2[d*32+u];
  } else if (tid < 108) sm[12224+(tid-96)] = W2[d*12+(tid-96)];
  else if (tid < 112)   sm[12236+(tid-108)] = b2[d*4+(tid-108)];

  // ---- stage W1T @9792 (170 f4), AT[z] @10472, WL0 @8704 (272 f4) ----
  {
    const f4* s4 = (const f4*)(w1T_all + (size_t)d*680);
    if (tid < 170) ((f4*)&sm[9792])[tid] = s4[tid];
  }
  for (int i = tid; i < 1280; i += 256) {
    int z2 = i / 640, tt = i % 640;
    sm[10472 + z2*680 + (tt%10)*68 + tt/10] =
      x[((size_t)((b0+z2)*Dv + d))*640 + tt];
  }
  const f4* wlsrc = (const f4*)(wlT_all + (size_t)d*8704);
  {
    ((f4*)&sm[8704])[tid] = wlsrc[tid];
    if (tid < 16) ((f4*)&sm[8704])[tid+256] = wlsrc[tid+256];
  }
  __syncthreads();

  // ---- FE1 GEMM: fe[s=4tx+i][o=PJ(j)], K=10 ----
  float fe[4][8];
  #pragma unroll
  for (int i=0;i<4;++i)
    #pragma unroll
    for (int j=0;j<8;++j) fe[i][j]=0.f;
  #pragma unroll
  for (int w = 0; w < 10; ++w) {
    f4 a   = *(const f4*)&sm[10472 + z*680 + w*68 + 4*tx];
    f4 blo = *(const f4*)&sm[9792 + w*68 + 4*ty];
    f4 bhi = *(const f4*)&sm[9792 + w*68 + 32 + 4*ty];
    float bv8[8] = {blo[0],blo[1],blo[2],blo[3],bhi[0],bhi[1],bhi[2],bhi[3]};
    #pragma unroll
    for (int i=0;i<4;++i)
      #pragma unroll
      for (int j=0;j<8;++j) fe[i][j] += a[i]*bv8[j];
  }
  #pragma unroll
  for (int j=0;j<8;++j) {
    int o = PJ(j);
    float bb = sm[12032+o];
    f4 v = {leaky(fe[0][j]+bb), leaky(fe[1][j]+bb), leaky(fe[2][j]+bb), leaky(fe[3][j]+bb)};
    *(f4*)&sm[z*4352 + o*68 + 4*tx] = v;
  }
  __syncthreads();

  // ---- embed: 8 chunks K=16, single-buffer WL (reg prefetch), single MT ----
  float ea[4][8];
  #pragma unroll
  for (int i=0;i<4;++i)
    #pragma unroll
    for (int j=0;j<8;++j) ea[i][j]=0.f;

  f4 wr0, wr1;
  for (int c = 0; c < 8; ++c) {
    // conv phase: write WL(c) (c>0), conv(c) -> MT[z], prefetch WL(c+1)
    if (c > 0) {
      ((f4*)&sm[8704])[tid] = wr0;
      if (tid < 16) ((f4*)&sm[8704])[tid+256] = wr1;
    }
    {
      int s = t & 63, ioh = t >> 6;
      float* mdst = &sm[9792 + z*1088];
      const float* fsrc = &sm[z*4352];
      #pragma unroll
      for (int io2=0; io2<2; ++io2) {
        int io = 2*ioh + io2;
        int fi = 4*c + io;
        if (fi <= 30) {
          int t0 = 2*fi - 1;
          float v0 = (t0 < 0) ? 0.f : fsrc[t0*68+s];
          float v1 = fsrc[(t0+1)*68+s];
          float v2 = fsrc[(t0+2)*68+s];
          float v3 = fsrc[(t0+3)*68+s];
          float v4 = fsrc[(t0+4)*68+s];
          #pragma unroll
          for (int ch=0; ch<4; ++ch) {
            float w0=sm[12224+ch*3], w1=sm[12224+ch*3+1], w2=sm[12224+ch*3+2];
            float bb=sm[12236+ch];
            float ca = bb + v0*w0 + v1*w1 + v2*w2;
            float cb = bb + v1*w0 + v2*w1 + v3*w2;
            float cc = bb + v2*w0 + v3*w1 + v4*w2;
            mdst[(ch*4+io)*68+s] = fmaxf(fmaxf(leaky(ca),leaky(cb)),leaky(cc));
          }
        }
      }
    }
    if (c < 7) {
      wr0 = wlsrc[(c+1)*272 + tid];
      if (tid < 16) wr1 = wlsrc[(c+1)*272 + 256 + tid];
    }
    __syncthreads();
    // GEMM(c)
    {
      const float* ma = &sm[9792 + z*1088];
      #pragma unroll
      for (int q=0;q<16;++q){
        f4 a   = *(const f4*)&ma[q*68+4*tx];
        f4 blo = *(const f4*)&sm[8704 + q*68+4*ty];
        f4 bhi = *(const f4*)&sm[8704 + q*68+32+4*ty];
        float bv8[8] = {blo[0],blo[1],blo[2],blo[3],bhi[0],bhi[1],bhi[2],bhi[3]};
        #pragma unroll
        for (int i=0;i<4;++i)
          #pragma unroll
          for (int j=0;j<8;++j) ea[i][j] += a[i]*bv8[j];
      }
    }
    __syncthreads();
  }

  // ---- epilogue: e, eT, wq partials, stage Wv1T ----
  float ev[4][8];
  #pragma unroll
  for (int i=0;i<4;++i)
    #pragma unroll
    for (int j=0;j<8;++j) ev[i][j] = leaky(ea[i][j] + sm[12096 + PJ(j)]);

  {
    float* erow = e_ws + (size_t)bd * 4096;
    #pragma unroll
    for (int i=0;i<4;++i) {
      f4 lo = {ev[i][0],ev[i][1],ev[i][2],ev[i][3]};
      f4 hi = {ev[i][4],ev[i][5],ev[i][6],ev[i][7]};
      *(f4*)&erow[(4*tx+i)*64 + 4*ty] = lo;
      *(f4*)&erow[(4*tx+i)*64 + 32 + 4*ty] = hi;
    }
  }
  #pragma unroll
  for (int j=0;j<8;++j) {
    int o = PJ(j);
    f4 v = {ev[0][j],ev[1][j],ev[2][j],ev[3][j]};
    *(f4*)&sm[z*4352 + o*68 + 4*tx] = v;      // eT over f1T
  }
  #pragma unroll
  for (int i=0;i<4;++i) {
    float p = 0.f;
    #pragma unroll
    for (int j=0;j<8;++j) p += ev[i][j]*sm[12160 + PJ(j)];
    p += __shfl_xor(p, 16);
    p += __shfl_xor(p, 32);
    if ((ty & 3) == 0) sm[11520 + z*128 + wz*64 + 4*tx + i] = p;
  }
  // stage Wv1T (576 f4) @8704 — WL/MT regions dead
  {
    const f4* s4 = (const f4*)(wv1T_all + (size_t)d*2304);
    f4 a0 = s4[tid], a1 = s4[tid+256];
    ((f4*)&sm[8704])[tid] = a0;
    ((f4*)&sm[8704])[tid+256] = a1;
    if (tid < 64) ((f4*)&sm[8704])[tid+512] = s4[tid+512];
  }
  __syncthreads();

  // ---- wq reduce ----
  if (tid < 128) {
    int z2 = tid >> 6, r = tid & 63;
    float p = sm[11520 + z2*128 + r] + sm[11520 + z2*128 + 64 + r];
    wq2_ws[((size_t)(b0+z2)*64 + r)*Dv + d] = sigm(p + bq0);
  }

  // ---- v-GEMM: va[s=4tx+i][h=4ty+j], K=64 ----
  float va[4][4];
  #pragma unroll
  for (int i=0;i<4;++i)
    #pragma unroll
    for (int j=0;j<4;++j) va[i][j]=0.f;
  #pragma unroll 8
  for (int o = 0; o < 64; ++o) {
    f4 a  = *(const f4*)&sm[z*4352 + o*68 + 4*tx];
    f4 bb = *(const f4*)&sm[8704 + o*36 + 4*ty];
    #pragma unroll
    for (int i=0;i<4;++i)
      #pragma unroll
      for (int j=0;j<4;++j) va[i][j] += a[i]*bb[j];
  }
  #pragma unroll
  for (int i=0;i<4;++i)
    #pragma unroll
    for (int j=0;j<4;++j) va[i][j] += sm[12240 + 4*ty + j];

  // ---- LN partials via wave shuffle ----
  #pragma unroll
  for (int i=0;i<4;++i) {
    float ps=0.f, pq=0.f;
    #pragma unroll
    for (int j=0;j<4;++j) { ps += va[i][j]; pq += va[i][j]*va[i][j]; }
    ps += __shfl_xor(ps, 16); ps += __shfl_xor(ps, 32);
    pq += __shfl_xor(pq, 16); pq += __shfl_xor(pq, 32);
    if ((ty & 3) == 0) {
      sm[11008 + z*128 + wz*64 + 4*tx + i] = ps;
      sm[11264 + z*128 + wz*64 + 4*tx + i] = pq;
    }
  }
  __syncthreads();
  if (tid < 128) {
    int z2 = tid >> 6, r = tid & 63;
    float s_ = sm[11008 + z2*128 + r] + sm[11008 + z2*128 + 64 + r];
    float q_ = sm[11264 + z2*128 + r] + sm[11264 + z2*128 + 64 + r];
    float mu = s_*(1.f/32.f);
    float vr = q_*(1.f/32.f) - mu*mu;
    sm[11776 + z2*64 + r] = mu;
    sm[11904 + z2*64 + r] = rsqrtf(vr + EPSv);
  }
  __syncthreads();

  // ---- LN + wv partials ----
  #pragma unroll
  for (int i=0;i<4;++i) {
    float mu = sm[11776 + z*64 + 4*tx + i];
    float rs = sm[11904 + z*64 + 4*tx + i];
    float p = 0.f;
    #pragma unroll
    for (int j=0;j<4;++j) {
      int h = 4*ty + j;
      float vh = leaky(sm[12272+h]*(va[i][j]-mu)*rs + sm[12304+h]);
      p += vh*sm[12336+h];
    }
    p += __shfl_xor(p, 16);
    p += __shfl_xor(p, 32);
    if ((ty & 3) == 0) sm[11520 + z*128 + wz*64 + 4*tx + i] = p;
  }
  __syncthreads();
  if (tid < 128) {
    int z2 = tid >> 6, r = tid & 63;
    float p = sm[11520 + z2*128 + r] + sm[11520 + z2*128 + 64 + r];
    wv_ws[((size_t)((b0+z2)*Dv + d))*64 + r] = fmaxf(p + bv2[d], 0.f);
  }
#undef PJ
}

// ---------------- K2: fused Wb1+LN+Wb2+cumsum+Wk/wq -> score1 ----------------
__global__ __launch_bounds__(128) void k2_fused(
    const float* __restrict__ e_ws,
    const float* __restrict__ Wb1, const float* __restrict__ bb1,
    const float* __restrict__ lng, const float* __restrict__ lnb,
    const float* __restrict__ Wb2, const float* __restrict__ bb2,
    const float* __restrict__ Wk, const float* __restrict__ bk,
    const float* __restrict__ wq2_ws, float* __restrict__ score1)
{
  __shared__ float smem[16384];           // 64 KiB, phase-aliased
  float* bufA = smem;                     // 8192 f  [64][128]: EsT -> HnT -> AcmlT
  float* bufB = smem + 8192;              // 4096 f  [64][64]:  W1T -> pts/ptq/stats -> WkT[64][40]
  float* bufC = smem + 12288;             // 4096 f  [64][64]:  W2T -> pt2[128][9]

  const int tid = threadIdx.x;
  const int tx = tid & 15;
  const int ty = tid >> 4;                // 0..7
  const int bd0 = blockIdx.x * 2;
  const int bd1 = bd0 + 1;

#define RI(i) ((i) < 4 ? 4*tx + (i) : 64 + 4*tx + ((i)-4))
#define PJ(j) ((j) < 4 ? 4*ty + (j) : 32 + 4*ty + ((j)-4))

  // ---- stage EsT (bufA), W1T (bufB), W2T (bufC), transposed ----
  {
    const int r0 = tid & 15, c0 = tid >> 4;      // c0 0..7
    const f4* Esrc  = (const f4*)(e_ws + (size_t)bd0 * 4096);
    #pragma unroll
    for (int p = 0; p < 2; ++p) {
      int oc = c0 + 8*p;
      #pragma unroll
      for (int q = 0; q < 8; ++q) {
        int r = r0 + 16*q;
        f4 v = Esrc[r*16 + oc];
        #pragma unroll
        for (int k = 0; k < 4; ++k) bufA[(4*oc+k)*128 + r] = v[k];
      }
    }
    const f4* W1src = (const f4*)Wb1;
    const f4* W2src = (const f4*)Wb2;
    #pragma unroll
    for (int p = 0; p < 2; ++p) {
      int oc = c0 + 8*p;
      #pragma unroll
      for (int q = 0; q < 4; ++q) {
        int rr = r0 + 16*q;
        f4 v1 = W1src[rr*16 + oc];
        f4 v2 = W2src[rr*16 + oc];
        #pragma unroll
        for (int k = 0; k < 4; ++k) {
          bufB[(4*oc+k)*64 + rr] = v1[k];
          bufC[(4*oc+k)*64 + rr] = v2[k];
        }
      }
    }
  }
  __syncthreads();

  // per-thread column constants
  float bb1v[8], lngv[8], lnbv[8], bb2v[8];
  #pragma unroll
  for (int j=0;j<8;++j) {
    int p = PJ(j);
    bb1v[j]=bb1[p]; lngv[j]=lng[p]; lnbv[j]=lnb[p]; bb2v[j]=bb2[p];
  }

  // ---- GEMM1: h[r][p] = sum_o E[r][o]*Wb1[p][o] ----
  float h[8][8];
  #pragma unroll
  for (int i=0;i<8;++i)
    #pragma unroll
    for (int j=0;j<8;++j) h[i][j]=0.f;
  for (int o = 0; o < 64; ++o) {
    f4 al = *(const f4*)(bufA + o*128 + 4*tx);
    f4 ah = *(const f4*)(bufA + o*128 + 64 + 4*tx);
    f4 bl = *(const f4*)(bufB + o*64 + 4*ty);
    f4 bh = *(const f4*)(bufB + o*64 + 32 + 4*ty);
    float av[8] = {al[0],al[1],al[2],al[3],ah[0],ah[1],ah[2],ah[3]};
    float bv[8] = {bl[0],bl[1],bl[2],bl[3],bh[0],bh[1],bh[2],bh[3]};
    #pragma unroll
    for (int i=0;i<8;++i)
      #pragma unroll
      for (int j=0;j<8;++j) h[i][j] += av[i]*bv[j];
  }
  #pragma unroll
  for (int i=0;i<8;++i)
    #pragma unroll
    for (int j=0;j<8;++j) h[i][j] += bb1v[j];

  // ---- LN stats: partials in bufB (W1T dead) ----
  __syncthreads();
  float* pts = bufB;              // [128][9]
  float* ptq = bufB + 1152;       // [128][9]
  float* stmu = bufB + 2304;      // [128]
  float* strs = bufB + 2432;      // [128]
  #pragma unroll
  for (int i=0;i<8;++i) {
    float ps=0.f, pq=0.f;
    #pragma unroll
    for (int j=0;j<8;++j) { ps += h[i][j]; pq += h[i][j]*h[i][j]; }
    pts[RI(i)*9 + ty] = ps;
    ptq[RI(i)*9 + ty] = pq;
  }
  __syncthreads();
  {
    float s=0.f, q=0.f;
    #pragma unroll
    for (int y=0;y<8;++y) { s += pts[tid*9+y]; q += ptq[tid*9+y]; }
    float mu = s*(1.f/64.f);
    float va = q*(1.f/64.f) - mu*mu;
    stmu[tid] = mu;
    strs[tid] = rsqrtf(va + EPSv);
  }
  __syncthreads();

  // ---- normalize + leaky, write HnT into bufA (E dead) ----
  {
    float muv[8], rsv[8];
    #pragma unroll
    for (int i=0;i<8;++i) { muv[i]=stmu[RI(i)]; rsv[i]=strs[RI(i)]; }
    #pragma unroll
    for (int i=0;i<8;++i)
      #pragma unroll
      for (int j=0;j<8;++j) {
        float hn = leaky(lngv[j]*(h[i][j]-muv[i])*rsv[i] + lnbv[j]);
        bufA[PJ(j)*128 + RI(i)] = hn;
      }
  }
  __syncthreads();

  // ---- GEMM2: g[r][q] = sum_p Hn[r][p]*Wb2[q][p] ----
  float gacc[8][8];
  #pragma unroll
  for (int i=0;i<8;++i)
    #pragma unroll
    for (int j=0;j<8;++j) gacc[i][j]=0.f;
  for (int p = 0; p < 64; ++p) {
    f4 al = *(const f4*)(bufA + p*128 + 4*tx);
    f4 ah = *(const f4*)(bufA + p*128 + 64 + 4*tx);
    f4 bl = *(const f4*)(bufC + p*64 + 4*ty);
    f4 bh = *(const f4*)(bufC + p*64 + 32 + 4*ty);
    float av[8] = {al[0],al[1],al[2],al[3],ah[0],ah[1],ah[2],ah[3]};
    float bv[8] = {bl[0],bl[1],bl[2],bl[3],bh[0],bh[1],bh[2],bh[3]};
    #pragma unroll
    for (int i=0;i<8;++i)
      #pragma unroll
      for (int j=0;j<8;++j) gacc[i][j] += av[i]*bv[j];
  }
  #pragma unroll
  for (int i=0;i<8;++i)
    #pragma unroll
    for (int j=0;j<8;++j) gacc[i][j] = leaky(gacc[i][j] + bb2v[j]);

  // ---- cumsum over s (per 64-row group) via 16-lane segment scan ----
  #pragma unroll
  for (int j=0;j<8;++j) {
    {
      float c0=gacc[0][j], c1=c0+gacc[1][j], c2=c1+gacc[2][j], c3=c2+gacc[3][j];
      float incl = c3;
      #pragma unroll
      for (int dd=1; dd<16; dd<<=1) {
        float t = __shfl_up(incl, dd, 16);
        if ((tid & 15) >= dd) incl += t;
      }
      float ex = incl - c3;
      gacc[0][j]=ex+c0; gacc[1][j]=ex+c1; gacc[2][j]=ex+c2; gacc[3][j]=ex+c3;
    }
    {
      float c0=gacc[4][j], c1=c0+gacc[5][j], c2=c1+gacc[6][j], c3=c2+gacc[7][j];
      float incl = c3;
      #pragma unroll
      for (int dd=1; dd<16; dd<<=1) {
        float t = __shfl_up(incl, dd, 16);
        if ((tid & 15) >= dd) incl += t;
      }
      float ex = incl - c3;
      gacc[4][j]=ex+c0; gacc[5][j]=ex+c1; gacc[6][j]=ex+c2; gacc[7][j]=ex+c3;
    }
  }
  __syncthreads();

  // ---- write AcmlT into bufA; stage WkT [64][40] into bufB ----
  #pragma unroll
  for (int i=0;i<8;++i)
    #pragma unroll
    for (int j=0;j<8;++j) bufA[PJ(j)*128 + RI(i)] = gacc[i][j];
  for (int i2 = tid; i2 < 2560; i2 += 128) {
    int q = i2/40, k = i2%40;
    bufB[i2] = (k < Dv) ? Wk[k*64 + q] : 0.f;
  }
  __syncthreads();

  // ---- GEMM3: u[r][k] = sum_q acml[r][q]*Wk[k][q] (k<38) ----
  float u[8][4], u2[8][4];
  #pragma unroll
  for (int i=0;i<8;++i)
    #pragma unroll
    for (int j=0;j<4;++j) { u[i][j]=0.f; u2[i][j]=0.f; }
  for (int q = 0; q < 64; ++q) {
    f4 al = *(const f4*)(bufA + q*128 + 4*tx);
    f4 ah = *(const f4*)(bufA + q*128 + 64 + 4*tx);
    f4 b1v = *(const f4*)(bufB + q*40 + 4*ty);
    float av[8] = {al[0],al[1],al[2],al[3],ah[0],ah[1],ah[2],ah[3]};
    #pragma unroll
    for (int i=0;i<8;++i)
      #pragma unroll
      for (int j=0;j<4;++j) u[i][j] += av[i]*b1v[j];
    if (ty < 2) {
      f4 b2v = *(const f4*)(bufB + q*40 + 32 + 4*ty);
      #pragma unroll
      for (int i=0;i<8;++i)
        #pragma unroll
        for (int j=0;j<4;++j) u2[i][j] += av[i]*b2v[j];
    }
  }

  // ---- epilogue: sigm(u+bk)*wq, reduce over k -> score1 ----
  const int b0g = bd0/Dv, d0g = bd0%Dv, b1g = bd1/Dv, d1g = bd1%Dv;
  float* pt2 = bufC;   // [128][9]
  #pragma unroll
  for (int i=0;i<8;++i) {
    int s = 4*tx + (i & 3);
    int bb_ = (i<4) ? b0g : b1g;
    const float* wqrow = wq2_ws + ((size_t)bb_*Sv + s)*Dv;
    float p = 0.f;
    #pragma unroll
    for (int j=0;j<4;++j) {
      int k = 4*ty + j;
      p += sigm(u[i][j] + bk[k]) * wqrow[k];
    }
    if (ty < 2) {
      #pragma unroll
      for (int j=0;j<4;++j) {
        int k = 32 + 4*ty + j;
        if (k < Dv) p += sigm(u2[i][j] + bk[k]) * wqrow[k];
      }
    }
    pt2[RI(i)*9 + ty] = p;
  }
  __syncthreads();
  {
    int rr = tid;                 // 0..127
    float tot = 0.f;
    #pragma unroll
    for (int y=0;y<8;++y) tot += pt2[rr*9+y];
    int grp = rr >> 6, s = rr & 63;
    int bb_ = grp ? b1g : b0g;
    int dd_ = grp ? d1g : d0g;
    score1[((size_t)bb_*Sv + s)*Dv + dd_] = tot;
  }
#undef RI
#undef PJ
}

// ---------------- K3: att1 softmax + contributes1/output1 + wq_a ----------------
__global__ __launch_bounds__(256) void k3_att1(
    const float* __restrict__ score1, const float* __restrict__ wv_ws,
    const float* __restrict__ e_ws, const float* __restrict__ Wq2, const float* __restrict__ bq2,
    float* __restrict__ out_c1, float* __restrict__ output1, float* __restrict__ wq_a)
{
  const int blk = blockIdx.x;
  const int b = blk / Sv, s = blk % Sv;
  const int tid = threadIdx.x;
  const int wid = tid>>6, lane = tid&63;
  __shared__ float red[4];

  if (wid==0) {
    const float invsq = 0.16222142113076254f; // 1/sqrt(38)
    float sc = (lane<Dv) ? score1[(b*Sv+s)*Dv+lane]*invsq : -1e30f;
    float mx = wmax64(sc);
    float ex = (lane<Dv) ? expf(sc-mx) : 0.f;
    float den = wred64(ex);
    float att = ex/den;
    float c1 = 0.f;
    if (lane<Dv) {
      c1 = wv_ws[(b*Dv+lane)*Sv+s]*att;
      out_c1[(b*Sv+s)*Dv+lane] = c1;
    }
    float tot = wred64(c1);
    if (lane==0) output1[b*Sv+s] = tot;
  }
  // wq_a[b,s] = sigmoid(ef[b,s]·Wq2 + bq2)
  float p = 0.f;
  for (int idx=tid; idx<Dv*64; idx+=256) {
    int d = idx>>6, o = idx&63;
    p += e_ws[((size_t)(b*Dv+d)*Sv+s)*64+o]*Wq2[idx];
  }
  p = wred64(p);
  if (lane==0) red[wid]=p;
  __syncthreads();
  if (tid==0) wq_a[b*Sv+s] = sigm(red[0]+red[1]+red[2]+red[3]+bq2[0]);
}

// ---------------- K4: per-b 64x64x2432 GEMM + fused score2 ----------------
__global__ __launch_bounds__(256) void k4_gemm(
    const float* __restrict__ e_ws, const float* __restrict__ Wk2, const float* __restrict__ bk2,
    const float* __restrict__ wq_a, float* __restrict__ score2)
{
  const int b = blockIdx.x;
  const int tid = threadIdx.x;
  const int tx = tid & 15, ty = tid >> 4;       // tile coords
  __shared__ float AsT[64*68];
  __shared__ float BsT[64*68];
  __shared__ float pt[64*17];

  float acc[4][4];
  #pragma unroll
  for (int i=0;i<4;++i)
    #pragma unroll
    for (int j=0;j<4;++j) acc[i][j]=0.f;

  const int r0 = tid & 15, oc0 = tid >> 4;      // staging map
  const f4* Bsrc = (const f4*)Wk2;              // row stride 608 f4

  for (int d = 0; d < 38; ++d) {
    const f4* Asrc = (const f4*)(e_ws + ((size_t)(b*Dv+d))*4096);
    #pragma unroll
    for (int q = 0; q < 4; ++q) {
      int r = r0 + 16*q;
      f4 av = Asrc[r*16 + oc0];
      f4 bv = Bsrc[(size_t)r*608 + d*16 + oc0];
      #pragma unroll
      for (int k = 0; k < 4; ++k) {
        AsT[(4*oc0+k)*68 + r] = av[k];
        BsT[(4*oc0+k)*68 + r] = bv[k];
      }
    }
    __syncthreads();
    #pragma unroll 4
    for (int o = 0; o < 64; ++o) {
      f4 a  = *(const f4*)&AsT[o*68 + 4*tx];
      f4 bb = *(const f4*)&BsT[o*68 + 4*ty];
      #pragma unroll
      for (int i=0;i<4;++i)
        #pragma unroll
        for (int j=0;j<4;++j) acc[i][j] += a[i]*bb[j];
    }
    __syncthreads();
  }

  // epilogue: score2[b,t] = sum_s sigm(C[t,s]+bk2[s])*wq_a[b,s]
  #pragma unroll
  for (int i=0;i<4;++i) {
    float p = 0.f;
    #pragma unroll
    for (int j=0;j<4;++j) {
      int s = 4*ty + j;
      p += sigm(acc[i][j] + bk2[s]) * wq_a[b*Sv + s];
    }
    pt[(4*tx+i)*17 + ty] = p;
  }
  __syncthreads();
  if (tid < 64) {
    float tot = 0.f;
    #pragma unroll
    for (int y=0;y<16;++y) tot += pt[tid*17+y];
    score2[b*Sv + tid] = tot;
  }
}

// ---------------- K5: att2 softmax + contributes2/output2 ----------------
__global__ __launch_bounds__(64) void k5_final(
    const float* __restrict__ score2, const float* __restrict__ output1,
    float* __restrict__ out)
{
  const int b = blockIdx.x;
  const int lane = threadIdx.x;
  const float inv = 0.039528470752104741f; // 1/sqrt(640)
  float v = score2[b*Sv+lane]*inv;
  float mx = wmax64(v);
  float ex = expf(v-mx);
  float den = wred64(ex);
  float att = ex/den;
  float c2 = output1[b*Sv+lane]*att;
  out[256 + b*Sv + lane] = c2;     // contributes2
  float tot = wred64(c2);
  if (lane==0) out[b] = tot;       // output2
}

extern "C" void kernel_launch(void* const* d_in, const int* in_sizes, int n_in,
                              void* d_out, int out_size, void* d_ws, size_t ws_size,
                              hipStream_t stream)
{
  const float* x    = (const float*)d_in[0];
  const float* W1   = (const float*)d_in[1];
  const float* b1   = (const float*)d_in[2];
  const float* W2   = (const float*)d_in[3];
  const float* b2   = (const float*)d_in[4];
  const float* Wl   = (const float*)d_in[5];
  const float* bl   = (const float*)d_in[6];
  const float* Wb1  = (const float*)d_in[7];
  const float* bb1  = (const float*)d_in[8];
  const float* lng  = (const float*)d_in[9];
  const float* lnb  = (const float*)d_in[10];
  const float* Wb2  = (const float*)d_in[11];
  const float* bb2  = (const float*)d_in[12];
  const float* Wq   = (const float*)d_in[13];
  const float* bq   = (const float*)d_in[14];
  const float* Wk   = (const float*)d_in[15];
  const float* bk   = (const float*)d_in[16];
  const float* Wv1  = (const float*)d_in[17];
  const float* bv1  = (const float*)d_in[18];
  const float* lnvg = (const float*)d_in[19];
  const float* lnvb = (const float*)d_in[20];
  const float* Wv2  = (const float*)d_in[21];
  const float* bv2  = (const float*)d_in[22];
  const float* Wq2  = (const float*)d_in[23];
  const float* bq2  = (const float*)d_in[24];
  const float* Wk2  = (const float*)d_in[25];
  const float* bk2  = (const float*)d_in[26];

  float* ws = (float*)d_ws;
  float* e_ws  = ws;                                   // B*D*S*64
  float* wq2w  = e_ws + (size_t)Bv*Dv*Sv*64;           // B*S*D  ([b][s][k])
  float* wv_ws = wq2w + (size_t)Bv*Sv*Dv;              // B*D*S
  float* sc1   = wv_ws + (size_t)Bv*Dv*Sv;             // B*S*D
  float* out1  = sc1 + (size_t)Bv*Sv*Dv;               // B*S
  float* wqa   = out1 + (size_t)Bv*Sv;                 // B*S
  float* sc2   = wqa + (size_t)Bv*Sv;                  // B*S
  float* wlT   = sc2 + (size_t)Bv*Sv;                  // 38*8*16*68 = 330752
  float* w1T   = wlT + 330752;                         // 38*10*68 = 25840
  float* wv1T  = w1T + 25840;                          // 38*64*36 = 87552

  float* out = (float*)d_out;
  float* out_c1 = out + 256 + Bv*Sv;                   // contributes1 offset

  hipLaunchKernelGGL(k0_pack, dim3(1736), dim3(256), 0, stream,
    Wl, W1, Wv1, wlT, w1T, wv1T);
  hipLaunchKernelGGL(k1_fe4, dim3(Dv*128), dim3(256), 0, stream,
    x, w1T, b1, W2, b2, wlT, bl, Wq, bq, wv1T, bv1, lnvg, lnvb, Wv2, bv2,
    e_ws, wq2w, wv_ws);
  hipLaunchKernelGGL(k2_fused, dim3(Bv*Dv/2), dim3(128), 0, stream,
    e_ws, Wb1, bb1, lng, lnb, Wb2, bb2, Wk, bk, wq2w, sc1);
  hipLaunchKernelGGL(k3_att1, dim3(Bv*Sv), dim3(256), 0, stream,
    sc1, wv_ws, e_ws, Wq2, bq2, out_c1, out1, wqa);
  hipLaunchKernelGGL(k4_gemm, dim3(Bv), dim3(256), 0, stream,
    e_ws, Wk2, bk2, wqa, sc2);
  hipLaunchKernelGGL(k5_final, dim3(Bv), dim3(64), 0, stream, sc2, out1, out);
}